// Round 1
// baseline (686.180 us; speedup 1.0000x reference)
//
#include <hip/hip_runtime.h>
#include <math.h>

#define MAXNORM 0.996f  // (1 - 4e-3) / sqrt(c), c = 1

__device__ __forceinline__ float wave_sum(float v) {
#pragma unroll
  for (int off = 32; off > 0; off >>= 1) v += __shfl_xor(v, off, 64);
  return v;
}

__device__ __forceinline__ float artanh_c(float x) {
  x = fminf(fmaxf(x, -1.0f + 1e-7f), 1.0f - 1e-7f);
  return 0.5f * (log1pf(x) - log1pf(-x));
}

// proj onto ball: recompute norm over the row (lane holds comps v0, v1)
__device__ __forceinline__ void proj2(float& v0, float& v1) {
  float n = fmaxf(sqrtf(wave_sum(v0 * v0 + v1 * v1)), 1e-15f);
  if (n > MAXNORM) {
    float s = MAXNORM / n;
    v0 *= s;
    v1 *= s;
  }
}

// expmap0 (c=1) followed by proj
__device__ __forceinline__ void expmap0_proj(float& v0, float& v1) {
  float n = fmaxf(sqrtf(wave_sum(v0 * v0 + v1 * v1)), 1e-15f);
  float s = tanhf(n) / n;
  v0 *= s;
  v1 *= s;
  proj2(v0, v1);
}

// ---------- K1: hyp_bias = proj(expmap0(b)) ; store bias + ||bias||^2 ----------
__global__ void k_bias(const float* __restrict__ b, float* __restrict__ wsb) {
  int lane = threadIdx.x;  // 64 threads
  float b0 = b[lane], b1 = b[lane + 64];
  float nb = fmaxf(sqrtf(wave_sum(b0 * b0 + b1 * b1)), 1e-15f);
  float s = tanhf(nb) / nb;
  float h0 = b0 * s, h1 = b1 * s;
  proj2(h0, h1);
  float y2 = wave_sum(h0 * h0 + h1 * h1);
  wsb[lane] = h0;
  wsb[lane + 64] = h1;
  if (lane == 0) wsb[128] = y2;
}

// ---------- per-row HypLinear tail + logmap0 ----------
// lane holds components (lane) and (lane+64) of mx in v0/v1.
__device__ __forceinline__ void hyplinear_tail(float& v0, float& v1, float xn2,
                                               float hb0, float hb1, float y2) {
  unsigned long long nz = __ballot(v0 != 0.0f || v1 != 0.0f);
  float mxn = fmaxf(sqrtf(wave_sum(v0 * v0 + v1 * v1)), 1e-15f);
  float xn = fmaxf(sqrtf(xn2), 1e-15f);
  float s = tanhf(mxn / xn * artanh_c(xn)) / mxn;  // sc = 1
  if (nz == 0ull) s = 0.0f;                        // all(mx == 0) case
  v0 *= s;
  v1 *= s;
  proj2(v0, v1);
  // mobius_add(h, hyp_bias), c = 1
  float x2 = wave_sum(v0 * v0 + v1 * v1);
  float xy = wave_sum(v0 * hb0 + v1 * hb1);
  float A = 1.0f + 2.0f * xy + y2;
  float B = 1.0f - x2;
  float den = fmaxf(1.0f + 2.0f * xy + x2 * y2, 1e-15f);
  float inv = 1.0f / den;
  v0 = (A * v0 + B * hb0) * inv;
  v1 = (A * v1 + B * hb1) * inv;
  proj2(v0, v1);
  // logmap0
  float n = fmaxf(sqrtf(wave_sum(v0 * v0 + v1 * v1)), 1e-15f);
  float ss = artanh_c(n) / n;
  v0 *= ss;
  v1 *= ss;
}

// ---------- K2: fused matvec + HypLinear + logmap0 -> xt ----------
// W staged in LDS with XOR swizzle: W[row][col] at Ws[row*128 + (col ^ (row&31))]
// Each wave processes 2 rows of x per iteration; lane computes output comps
// (lane) and (lane+64).
__global__ __launch_bounds__(256, 2) void k_linear(
    const float* __restrict__ x, const float* __restrict__ W,
    const float* __restrict__ wsb, float* __restrict__ xt, int nPairs) {
  __shared__ float Ws[128 * 128];
  const int t = threadIdx.x;
#pragma unroll 4
  for (int idx = t; idx < 128 * 128; idx += 256) {
    int row = idx >> 7, col = idx & 127;
    Ws[(row << 7) | (col ^ (row & 31))] = W[idx];
  }
  const int lane = t & 63;
  const int wv = t >> 6;
  float hb0 = wsb[lane], hb1 = wsb[lane + 64];
  float y2 = wsb[128];
  __syncthreads();

  const int gw = blockIdx.x * 4 + wv;
  const int stride = gridDim.x * 4;
  const int rbase0 = lane << 7;
  const int rbase1 = (lane + 64) << 7;
  const int lx = lane & 31;

  for (int p = gw; p < nPairs; p += stride) {
    size_t r0 = (size_t)(2 * p), r1 = r0 + 1;
    float2 xa = ((const float2*)(x + r0 * 128))[lane];
    float2 xb = ((const float2*)(x + r1 * 128))[lane];
    float xn2a = wave_sum(xa.x * xa.x + xa.y * xa.y);
    float xn2b = wave_sum(xb.x * xb.x + xb.y * xb.y);

    float aA0 = 0.f, aA1 = 0.f, aB0 = 0.f, aB1 = 0.f;
#pragma unroll 8
    for (int jj = 0; jj < 64; ++jj) {
      float xA0 = __uint_as_float(__builtin_amdgcn_readlane(__float_as_uint(xa.x), jj));
      float xA1 = __uint_as_float(__builtin_amdgcn_readlane(__float_as_uint(xa.y), jj));
      float xB0 = __uint_as_float(__builtin_amdgcn_readlane(__float_as_uint(xb.x), jj));
      float xB1 = __uint_as_float(__builtin_amdgcn_readlane(__float_as_uint(xb.y), jj));
      int j0 = (2 * jj) ^ lx;
      int j1 = j0 ^ 1;
      float w00 = Ws[rbase0 + j0];  // W[lane][2jj]
      float w01 = Ws[rbase0 + j1];  // W[lane][2jj+1]
      float w10 = Ws[rbase1 + j0];  // W[lane+64][2jj]
      float w11 = Ws[rbase1 + j1];  // W[lane+64][2jj+1]
      aA0 = fmaf(w00, xA0, aA0);
      aA0 = fmaf(w01, xA1, aA0);
      aA1 = fmaf(w10, xA0, aA1);
      aA1 = fmaf(w11, xA1, aA1);
      aB0 = fmaf(w00, xB0, aB0);
      aB0 = fmaf(w01, xB1, aB0);
      aB1 = fmaf(w10, xB0, aB1);
      aB1 = fmaf(w11, xB1, aB1);
    }

    {
      float v0 = aA0, v1 = aA1;
      hyplinear_tail(v0, v1, xn2a, hb0, hb1, y2);
      xt[r0 * 128 + lane] = v0;
      xt[r0 * 128 + 64 + lane] = v1;
    }
    {
      float v0 = aB0, v1 = aB1;
      hyplinear_tail(v0, v1, xn2b, hb0, hb1, y2);
      xt[r1 * 128 + lane] = v0;
      xt[r1 * 128 + 64 + lane] = v1;
    }
  }
}

// ---------- K3: edge gather + weighted scatter-add ----------
__global__ void k_edge(const float* __restrict__ xt, const float* __restrict__ ew,
                       const int* __restrict__ src, const int* __restrict__ dst,
                       float* __restrict__ agg, int E) {
  int tid = blockIdx.x * blockDim.x + threadIdx.x;
  int gw = tid >> 6;
  int lane = tid & 63;
  int nw = (gridDim.x * blockDim.x) >> 6;
  for (int e = gw; e < E; e += nw) {
    int s = src[e];
    int d = dst[e];
    float wgt = ew[e];
    float2 v = ((const float2*)(xt + (size_t)s * 128))[lane];
    float* base = agg + (size_t)d * 128 + 2 * lane;
    unsafeAtomicAdd(base, v.x * wgt);
    unsafeAtomicAdd(base + 1, v.y * wgt);
  }
}

// ---------- K4: h = proj(expmap0(agg)); out = proj(expmap0(relu(logmap0(h)))) ----------
__global__ void k_final(const float* __restrict__ agg, float* __restrict__ out, int N) {
  int gw = blockIdx.x * 4 + (threadIdx.x >> 6);
  int lane = threadIdx.x & 63;
  if (gw >= N) return;
  float2 v = ((const float2*)(agg + (size_t)gw * 128))[lane];
  float v0 = v.x, v1 = v.y;
  expmap0_proj(v0, v1);  // h = proj(expmap0(agg))
  // t = relu(logmap0(h))
  float n = fmaxf(sqrtf(wave_sum(v0 * v0 + v1 * v1)), 1e-15f);
  float s = artanh_c(n) / n;
  v0 = fmaxf(v0 * s, 0.0f);
  v1 = fmaxf(v1 * s, 0.0f);
  expmap0_proj(v0, v1);  // out = proj(expmap0(t))
  ((float2*)(out + (size_t)gw * 128))[lane] = make_float2(v0, v1);
}

extern "C" void kernel_launch(void* const* d_in, const int* in_sizes, int n_in,
                              void* d_out, int out_size, void* d_ws, size_t ws_size,
                              hipStream_t stream) {
  const float* x = (const float*)d_in[0];
  const float* W = (const float*)d_in[1];
  const float* b = (const float*)d_in[2];
  const float* ew = (const float*)d_in[3];
  const int* src = (const int*)d_in[4];
  const int* dst = (const int*)d_in[5];
  float* out = (float*)d_out;
  const int N = in_sizes[0] / 128;
  const int E = in_sizes[3];

  float* wsb = (float*)d_ws;   // 129 floats (padded to 256)
  float* agg = wsb + 256;      // N*128 floats

  hipMemsetAsync(agg, 0, (size_t)N * 128 * sizeof(float), stream);
  k_bias<<<1, 64, 0, stream>>>(b, wsb);
  // xt is staged in d_out (fully overwritten before k_final rewrites it)
  k_linear<<<512, 256, 0, stream>>>(x, W, wsb, out, N / 2);
  k_edge<<<2048, 256, 0, stream>>>(out, ew, src, dst, agg, E);
  k_final<<<(N + 3) / 4, 256, 0, stream>>>(agg, out, N);
}

// Round 2
// 331.807 us; speedup vs baseline: 2.0680x; 2.0680x over previous
//
#include <hip/hip_runtime.h>
#include <math.h>

#define MAXNORM 0.996f  // (1 - 4e-3) / sqrt(c), c = 1

__device__ __forceinline__ float wave_sum(float v) {
#pragma unroll
  for (int off = 32; off > 0; off >>= 1) v += __shfl_xor(v, off, 64);
  return v;
}

__device__ __forceinline__ float artanh_c(float x) {
  x = fminf(fmaxf(x, -1.0f + 1e-7f), 1.0f - 1e-7f);
  return 0.5f * (log1pf(x) - log1pf(-x));
}

// proj onto ball: recompute norm over the row (lane holds comps v0, v1)
__device__ __forceinline__ void proj2(float& v0, float& v1) {
  float n = fmaxf(sqrtf(wave_sum(v0 * v0 + v1 * v1)), 1e-15f);
  if (n > MAXNORM) {
    float s = MAXNORM / n;
    v0 *= s;
    v1 *= s;
  }
}

// expmap0 (c=1) followed by proj
__device__ __forceinline__ void expmap0_proj(float& v0, float& v1) {
  float n = fmaxf(sqrtf(wave_sum(v0 * v0 + v1 * v1)), 1e-15f);
  float s = tanhf(n) / n;
  v0 *= s;
  v1 *= s;
  proj2(v0, v1);
}

// ---------- K1: hyp_bias = proj(expmap0(b)) ; store bias + ||bias||^2 ----------
__global__ void k_bias(const float* __restrict__ b, float* __restrict__ wsb) {
  int lane = threadIdx.x;  // 64 threads
  float b0 = b[lane], b1 = b[lane + 64];
  float nb = fmaxf(sqrtf(wave_sum(b0 * b0 + b1 * b1)), 1e-15f);
  float s = tanhf(nb) / nb;
  float h0 = b0 * s, h1 = b1 * s;
  proj2(h0, h1);
  float y2 = wave_sum(h0 * h0 + h1 * h1);
  wsb[lane] = h0;
  wsb[lane + 64] = h1;
  if (lane == 0) wsb[128] = y2;
}

// ---------- per-row HypLinear tail + logmap0 ----------
__device__ __forceinline__ void hyplinear_tail(float& v0, float& v1, float xn2,
                                               float hb0, float hb1, float y2) {
  unsigned long long nz = __ballot(v0 != 0.0f || v1 != 0.0f);
  float mxn = fmaxf(sqrtf(wave_sum(v0 * v0 + v1 * v1)), 1e-15f);
  float xn = fmaxf(sqrtf(xn2), 1e-15f);
  float s = tanhf(mxn / xn * artanh_c(xn)) / mxn;  // sc = 1
  if (nz == 0ull) s = 0.0f;                        // all(mx == 0) case
  v0 *= s;
  v1 *= s;
  proj2(v0, v1);
  // mobius_add(h, hyp_bias), c = 1
  float x2 = wave_sum(v0 * v0 + v1 * v1);
  float xy = wave_sum(v0 * hb0 + v1 * hb1);
  float A = 1.0f + 2.0f * xy + y2;
  float B = 1.0f - x2;
  float den = fmaxf(1.0f + 2.0f * xy + x2 * y2, 1e-15f);
  float inv = 1.0f / den;
  v0 = (A * v0 + B * hb0) * inv;
  v1 = (A * v1 + B * hb1) * inv;
  proj2(v0, v1);
  // logmap0
  float n = fmaxf(sqrtf(wave_sum(v0 * v0 + v1 * v1)), 1e-15f);
  float ss = artanh_c(n) / n;
  v0 *= ss;
  v1 *= ss;
}

// ---------- K2: fused matvec + HypLinear + logmap0 -> xt ----------
__global__ __launch_bounds__(256, 2) void k_linear(
    const float* __restrict__ x, const float* __restrict__ W,
    const float* __restrict__ wsb, float* __restrict__ xt, int nPairs) {
  __shared__ float Ws[128 * 128];
  const int t = threadIdx.x;
#pragma unroll 4
  for (int idx = t; idx < 128 * 128; idx += 256) {
    int row = idx >> 7, col = idx & 127;
    Ws[(row << 7) | (col ^ (row & 31))] = W[idx];
  }
  const int lane = t & 63;
  const int wv = t >> 6;
  float hb0 = wsb[lane], hb1 = wsb[lane + 64];
  float y2 = wsb[128];
  __syncthreads();

  const int gw = blockIdx.x * 4 + wv;
  const int stride = gridDim.x * 4;
  const int rbase0 = lane << 7;
  const int rbase1 = (lane + 64) << 7;
  const int lx = lane & 31;

  for (int p = gw; p < nPairs; p += stride) {
    size_t r0 = (size_t)(2 * p), r1 = r0 + 1;
    float2 xa = ((const float2*)(x + r0 * 128))[lane];
    float2 xb = ((const float2*)(x + r1 * 128))[lane];
    float xn2a = wave_sum(xa.x * xa.x + xa.y * xa.y);
    float xn2b = wave_sum(xb.x * xb.x + xb.y * xb.y);

    float aA0 = 0.f, aA1 = 0.f, aB0 = 0.f, aB1 = 0.f;
#pragma unroll 8
    for (int jj = 0; jj < 64; ++jj) {
      float xA0 = __uint_as_float(__builtin_amdgcn_readlane(__float_as_uint(xa.x), jj));
      float xA1 = __uint_as_float(__builtin_amdgcn_readlane(__float_as_uint(xa.y), jj));
      float xB0 = __uint_as_float(__builtin_amdgcn_readlane(__float_as_uint(xb.x), jj));
      float xB1 = __uint_as_float(__builtin_amdgcn_readlane(__float_as_uint(xb.y), jj));
      int j0 = (2 * jj) ^ lx;
      int j1 = j0 ^ 1;
      float w00 = Ws[rbase0 + j0];
      float w01 = Ws[rbase0 + j1];
      float w10 = Ws[rbase1 + j0];
      float w11 = Ws[rbase1 + j1];
      aA0 = fmaf(w00, xA0, aA0);
      aA0 = fmaf(w01, xA1, aA0);
      aA1 = fmaf(w10, xA0, aA1);
      aA1 = fmaf(w11, xA1, aA1);
      aB0 = fmaf(w00, xB0, aB0);
      aB0 = fmaf(w01, xB1, aB0);
      aB1 = fmaf(w10, xB0, aB1);
      aB1 = fmaf(w11, xB1, aB1);
    }

    {
      float v0 = aA0, v1 = aA1;
      hyplinear_tail(v0, v1, xn2a, hb0, hb1, y2);
      xt[r0 * 128 + lane] = v0;
      xt[r0 * 128 + 64 + lane] = v1;
    }
    {
      float v0 = aB0, v1 = aB1;
      hyplinear_tail(v0, v1, xn2b, hb0, hb1, y2);
      xt[r1 * 128 + lane] = v0;
      xt[r1 * 128 + 64 + lane] = v1;
    }
  }
}

// ---------- CSR build ----------
__global__ void k_hist(const int* __restrict__ dst, int* __restrict__ deg, int E) {
  int e = blockIdx.x * blockDim.x + threadIdx.x;
  if (e < E) atomicAdd(&deg[dst[e]], 1);
}

// single-block exclusive scan over deg[0..N) -> offsets[0..N]
__global__ __launch_bounds__(1024) void k_scan(const int* __restrict__ deg,
                                               int* __restrict__ offsets, int N) {
  __shared__ int waveSums[16];
  __shared__ int sCarry;
  int t = threadIdx.x;
  int lane = t & 63, wv = t >> 6;
  if (t == 0) sCarry = 0;
  __syncthreads();
  for (int base = 0; base < N; base += 1024) {
    int i = base + t;
    int v = (i < N) ? deg[i] : 0;
    int incl = v;
#pragma unroll
    for (int off = 1; off < 64; off <<= 1) {
      int u = __shfl_up(incl, off, 64);
      if (lane >= off) incl += u;
    }
    if (lane == 63) waveSums[wv] = incl;
    __syncthreads();
    if (wv == 0) {
      int s = (lane < 16) ? waveSums[lane] : 0;
#pragma unroll
      for (int off = 1; off < 16; off <<= 1) {
        int u = __shfl_up(s, off, 64);
        if (lane >= off) s += u;
      }
      if (lane < 16) waveSums[lane] = s;  // inclusive wave-sum scan
    }
    __syncthreads();
    int waveOff = (wv == 0) ? 0 : waveSums[wv - 1];
    int excl = sCarry + waveOff + incl - v;
    if (i < N) offsets[i] = excl;
    __syncthreads();
    if (t == 0) sCarry += waveSums[15];
    __syncthreads();
  }
  if (t == 0) offsets[N] = sCarry;
}

// scatter edges into CSR; offsets[n] is bumped to end-of-segment
__global__ void k_scatter(const int* __restrict__ src, const int* __restrict__ dst,
                          const float* __restrict__ ew, int* __restrict__ offsets,
                          int* __restrict__ csr_src, float* __restrict__ csr_w, int E) {
  int e = blockIdx.x * blockDim.x + threadIdx.x;
  if (e < E) {
    int p = atomicAdd(&offsets[dst[e]], 1);
    csr_src[p] = src[e];
    csr_w[p] = ew[e];
  }
}

// ---------- fused: gather-aggregate + expmap0/proj + relu(logmap0) + expmap0/proj ----------
__global__ __launch_bounds__(256) void k_agg_final(
    const float* __restrict__ xt, const int* __restrict__ csr_src,
    const float* __restrict__ csr_w, const int* __restrict__ offsets,
    const int* __restrict__ deg, float* __restrict__ out, int N) {
  int n = blockIdx.x * 4 + (threadIdx.x >> 6);
  int lane = threadIdx.x & 63;
  if (n >= N) return;
  int end = offsets[n];  // post-scatter: end of segment
  int dg = deg[n];
  int e = end - dg;
  float a0 = 0.f, a1 = 0.f;
  for (; e + 2 <= end; e += 2) {
    int s0 = csr_src[e], s1 = csr_src[e + 1];
    float w0 = csr_w[e], w1 = csr_w[e + 1];
    float2 u0 = ((const float2*)(xt + (size_t)s0 * 128))[lane];
    float2 u1 = ((const float2*)(xt + (size_t)s1 * 128))[lane];
    a0 = fmaf(w0, u0.x, a0);
    a1 = fmaf(w0, u0.y, a1);
    a0 = fmaf(w1, u1.x, a0);
    a1 = fmaf(w1, u1.y, a1);
  }
  if (e < end) {
    int s0 = csr_src[e];
    float w0 = csr_w[e];
    float2 u0 = ((const float2*)(xt + (size_t)s0 * 128))[lane];
    a0 = fmaf(w0, u0.x, a0);
    a1 = fmaf(w0, u0.y, a1);
  }
  float v0 = a0, v1 = a1;
  expmap0_proj(v0, v1);  // h = proj(expmap0(agg))
  float nn = fmaxf(sqrtf(wave_sum(v0 * v0 + v1 * v1)), 1e-15f);
  float s = artanh_c(nn) / nn;
  v0 = fmaxf(v0 * s, 0.0f);
  v1 = fmaxf(v1 * s, 0.0f);
  expmap0_proj(v0, v1);  // out = proj(expmap0(t))
  ((float2*)(out + (size_t)n * 128))[lane] = make_float2(v0, v1);
}

// ---------- fallback path (round-1): edge atomics ----------
__global__ void k_edge(const float* __restrict__ xt, const float* __restrict__ ew,
                       const int* __restrict__ src, const int* __restrict__ dst,
                       float* __restrict__ agg, int E) {
  int tid = blockIdx.x * blockDim.x + threadIdx.x;
  int gw = tid >> 6;
  int lane = tid & 63;
  int nw = (gridDim.x * blockDim.x) >> 6;
  for (int e = gw; e < E; e += nw) {
    int s = src[e];
    int d = dst[e];
    float wgt = ew[e];
    float2 v = ((const float2*)(xt + (size_t)s * 128))[lane];
    float* base = agg + (size_t)d * 128 + 2 * lane;
    unsafeAtomicAdd(base, v.x * wgt);
    unsafeAtomicAdd(base + 1, v.y * wgt);
  }
}

__global__ void k_final(const float* __restrict__ agg, float* __restrict__ out, int N) {
  int gw = blockIdx.x * 4 + (threadIdx.x >> 6);
  int lane = threadIdx.x & 63;
  if (gw >= N) return;
  float2 v = ((const float2*)(agg + (size_t)gw * 128))[lane];
  float v0 = v.x, v1 = v.y;
  expmap0_proj(v0, v1);
  float n = fmaxf(sqrtf(wave_sum(v0 * v0 + v1 * v1)), 1e-15f);
  float s = artanh_c(n) / n;
  v0 = fmaxf(v0 * s, 0.0f);
  v1 = fmaxf(v1 * s, 0.0f);
  expmap0_proj(v0, v1);
  ((float2*)(out + (size_t)gw * 128))[lane] = make_float2(v0, v1);
}

static inline size_t pad256(size_t x) { return (x + 255) & ~(size_t)255; }

extern "C" void kernel_launch(void* const* d_in, const int* in_sizes, int n_in,
                              void* d_out, int out_size, void* d_ws, size_t ws_size,
                              hipStream_t stream) {
  const float* x = (const float*)d_in[0];
  const float* W = (const float*)d_in[1];
  const float* b = (const float*)d_in[2];
  const float* ew = (const float*)d_in[3];
  const int* src = (const int*)d_in[4];
  const int* dst = (const int*)d_in[5];
  float* out = (float*)d_out;
  const int N = in_sizes[0] / 128;
  const int E = in_sizes[3];

  // CSR-path workspace layout
  char* p = (char*)d_ws;
  float* wsb = (float*)p;      p += 1024;
  int* deg = (int*)p;          p += pad256((size_t)N * 4);
  int* offsets = (int*)p;      p += pad256((size_t)(N + 1) * 4);
  int* csr_src = (int*)p;      p += pad256((size_t)E * 4);
  float* csr_w = (float*)p;    p += pad256((size_t)E * 4);
  float* xt = (float*)p;       p += (size_t)N * 512;
  size_t need = (size_t)(p - (char*)d_ws);

  if (ws_size >= need) {
    // ---- CSR gather-side path ----
    hipMemsetAsync(deg, 0, (size_t)N * 4, stream);
    k_bias<<<1, 64, 0, stream>>>(b, wsb);
    k_hist<<<(E + 255) / 256, 256, 0, stream>>>(dst, deg, E);
    k_scan<<<1, 1024, 0, stream>>>(deg, offsets, N);
    k_linear<<<512, 256, 0, stream>>>(x, W, wsb, xt, N / 2);
    k_scatter<<<(E + 255) / 256, 256, 0, stream>>>(src, dst, ew, offsets, csr_src, csr_w, E);
    k_agg_final<<<(N + 3) / 4, 256, 0, stream>>>(xt, csr_src, csr_w, offsets, deg, out, N);
  } else {
    // ---- fallback: round-1 atomic path ----
    float* wsb2 = (float*)d_ws;
    float* agg = wsb2 + 256;
    hipMemsetAsync(agg, 0, (size_t)N * 128 * sizeof(float), stream);
    k_bias<<<1, 64, 0, stream>>>(b, wsb2);
    k_linear<<<512, 256, 0, stream>>>(x, W, wsb2, out, N / 2);
    k_edge<<<2048, 256, 0, stream>>>(out, ew, src, dst, agg, E);
    k_final<<<(N + 3) / 4, 256, 0, stream>>>(agg, out, N);
  }
}

// Round 3
// 262.409 us; speedup vs baseline: 2.6149x; 1.2645x over previous
//
#include <hip/hip_runtime.h>
#include <math.h>

#define MAXNORM 0.996f  // (1 - 4e-3) / sqrt(c), c = 1

__device__ __forceinline__ float wave_sum(float v) {
#pragma unroll
  for (int off = 32; off > 0; off >>= 1) v += __shfl_xor(v, off, 64);
  return v;
}

__device__ __forceinline__ float artanh_c(float x) {
  x = fminf(fmaxf(x, -1.0f + 1e-7f), 1.0f - 1e-7f);
  return 0.5f * (log1pf(x) - log1pf(-x));
}

__device__ __forceinline__ void proj2(float& v0, float& v1) {
  float n = fmaxf(sqrtf(wave_sum(v0 * v0 + v1 * v1)), 1e-15f);
  if (n > MAXNORM) {
    float s = MAXNORM / n;
    v0 *= s;
    v1 *= s;
  }
}

__device__ __forceinline__ void expmap0_proj(float& v0, float& v1) {
  float n = fmaxf(sqrtf(wave_sum(v0 * v0 + v1 * v1)), 1e-15f);
  float s = tanhf(n) / n;
  v0 *= s;
  v1 *= s;
  proj2(v0, v1);
}

// ---------- K1: hyp_bias = proj(expmap0(b)) ; store bias + ||bias||^2 ----------
__global__ void k_bias(const float* __restrict__ b, float* __restrict__ wsb) {
  int lane = threadIdx.x;  // 64 threads
  float b0 = b[lane], b1 = b[lane + 64];
  float nb = fmaxf(sqrtf(wave_sum(b0 * b0 + b1 * b1)), 1e-15f);
  float s = tanhf(nb) / nb;
  float h0 = b0 * s, h1 = b1 * s;
  proj2(h0, h1);
  float y2 = wave_sum(h0 * h0 + h1 * h1);
  wsb[lane] = h0;
  wsb[lane + 64] = h1;
  if (lane == 0) wsb[128] = y2;
}

// ---------- K2: register-tiled GEMM (64 rows x 128 outs) + fused HypLinear tail ----------
// Thread (tn = t&15, tm = t>>4): rows 4tm..4tm+3, cols 8tn..8tn+7, acc[4][8].
// LDS: Ws[128][128] XOR-swizzled by ((row>>3)&7)<<2; xs[64][128] swizzled by ((row>>2)&7)<<2.
__global__ __launch_bounds__(256) void k_linear(
    const float* __restrict__ x, const float* __restrict__ W,
    const float* __restrict__ wsb, float* __restrict__ xt, int N) {
  __shared__ float Ws[128 * 128];
  __shared__ float xs[64 * 128];
  const int t = threadIdx.x;
  const int tn = t & 15;
  const int tm = t >> 4;

  // stage W (16384 floats = 4096 float4)
  const float4* W4 = (const float4*)W;
#pragma unroll
  for (int i = 0; i < 16; ++i) {
    int idx = t + 256 * i;
    int row = idx >> 5;
    int col4 = (idx & 31) << 2;
    int sw = ((row >> 3) & 7) << 2;
    float4 v = W4[idx];
    *(float4*)&Ws[row * 128 + (col4 ^ sw)] = v;
  }

  // bias fragment
  float hb[8];
  *(float4*)&hb[0] = *(const float4*)&wsb[8 * tn];
  *(float4*)&hb[4] = *(const float4*)&wsb[8 * tn + 4];
  const float y2 = wsb[128];

  const int tile0 = blockIdx.x * 64;

  // stage x tile (64 rows)
  const float4* X4 = (const float4*)x;
#pragma unroll
  for (int i = 0; i < 8; ++i) {
    int idx = t + 256 * i;
    int row = idx >> 5;
    int col4 = (idx & 31) << 2;
    int sw = ((row >> 2) & 7) << 2;
    int grow = tile0 + row;
    float4 v = make_float4(0.f, 0.f, 0.f, 0.f);
    if (grow < N) v = X4[(size_t)grow * 32 + (idx & 31)];
    *(float4*)&xs[row * 128 + (col4 ^ sw)] = v;
  }
  __syncthreads();

  float acc[4][8];
#pragma unroll
  for (int m = 0; m < 4; ++m)
#pragma unroll
    for (int n = 0; n < 8; ++n) acc[m][n] = 0.f;

  const int swx = (tm & 7) << 2;
  const int sww = (tn & 7) << 2;
  const int xbase = (tm * 4) * 128;
  const int wbase = (tn * 8) * 128;

#pragma unroll 4
  for (int kk = 0; kk < 32; ++kk) {
    const int k = kk << 2;
    const int xoff = xbase + (k ^ swx);
    const int woff = wbase + (k ^ sww);
    float4 xf[4], wf[8];
#pragma unroll
    for (int m = 0; m < 4; ++m) xf[m] = *(const float4*)&xs[xoff + m * 128];
#pragma unroll
    for (int n = 0; n < 8; ++n) wf[n] = *(const float4*)&Ws[woff + n * 128];
#pragma unroll
    for (int m = 0; m < 4; ++m)
#pragma unroll
      for (int n = 0; n < 8; ++n) {
        acc[m][n] = fmaf(xf[m].x, wf[n].x, acc[m][n]);
        acc[m][n] = fmaf(xf[m].y, wf[n].y, acc[m][n]);
        acc[m][n] = fmaf(xf[m].z, wf[n].z, acc[m][n]);
        acc[m][n] = fmaf(xf[m].w, wf[n].w, acc[m][n]);
      }
  }

  // fused tail: per row r = 4tm+m — reductions over the 16-lane tn group
#pragma unroll
  for (int m = 0; m < 4; ++m) {
    const int row = 4 * tm + m;
    const int grow = tile0 + row;
    // partial sums
    float4 u0 = *(const float4*)&xs[row * 128 + ((8 * tn) ^ swx)];
    float4 u1 = *(const float4*)&xs[row * 128 + ((8 * tn + 4) ^ swx)];
    float px = u0.x * u0.x + u0.y * u0.y + u0.z * u0.z + u0.w * u0.w +
               u1.x * u1.x + u1.y * u1.y + u1.z * u1.z + u1.w * u1.w;
    float pm = 0.f, pxy = 0.f;
#pragma unroll
    for (int n = 0; n < 8; ++n) {
      pm = fmaf(acc[m][n], acc[m][n], pm);
      pxy = fmaf(acc[m][n], hb[n], pxy);
    }
#pragma unroll
    for (int off = 1; off < 16; off <<= 1) {
      px += __shfl_xor(px, off, 64);
      pm += __shfl_xor(pm, off, 64);
      pxy += __shfl_xor(pxy, off, 64);
    }
    // scalar chain (per row, uniform across the 16 lanes)
    float xn = fmaxf(sqrtf(px), 1e-15f);
    float mxn = fmaxf(sqrtf(pm), 1e-15f);
    float s1 = tanhf(mxn / xn * artanh_c(xn)) / mxn;
    if (pm == 0.0f) s1 = 0.0f;
    float nv = s1 * mxn;  // s1 >= 0
    if (nv > MAXNORM) {
      s1 *= MAXNORM / nv;
      nv = MAXNORM;
    }
    float x2 = nv * nv;
    float xy = s1 * pxy;
    float A = 1.0f + 2.0f * xy + y2;
    float B = 1.0f - x2;
    float den = fmaxf(1.0f + 2.0f * xy + x2 * y2, 1e-15f);
    float rn2 = fmaxf(A * A * x2 + 2.0f * A * B * xy + B * B * y2, 0.0f);
    float rn = sqrtf(rn2) / den;
    float g = 1.0f;
    if (rn > MAXNORM) g = MAXNORM / rn;
    float ng = fmaxf(fminf(rn, MAXNORM), 1e-15f);
    float slog = artanh_c(ng) / ng;
    float ftot = slog * g / den;
    float f1 = ftot * A * s1;
    float f2 = ftot * B;
    if (grow < N) {
      float o[8];
#pragma unroll
      for (int n = 0; n < 8; ++n) o[n] = f1 * acc[m][n] + f2 * hb[n];
      *(float4*)&xt[(size_t)grow * 128 + 8 * tn] = make_float4(o[0], o[1], o[2], o[3]);
      *(float4*)&xt[(size_t)grow * 128 + 8 * tn + 4] = make_float4(o[4], o[5], o[6], o[7]);
    }
  }
}

// ---------- CSR build ----------
__global__ void k_hist(const int* __restrict__ dst, int* __restrict__ deg, int E) {
  int e = blockIdx.x * blockDim.x + threadIdx.x;
  if (e < E) atomicAdd(&deg[dst[e]], 1);
}

__global__ __launch_bounds__(1024) void k_scan(const int* __restrict__ deg,
                                               int* __restrict__ offsets, int N) {
  __shared__ int waveSums[16];
  __shared__ int sCarry;
  int t = threadIdx.x;
  int lane = t & 63, wv = t >> 6;
  if (t == 0) sCarry = 0;
  __syncthreads();
  for (int base = 0; base < N; base += 1024) {
    int i = base + t;
    int v = (i < N) ? deg[i] : 0;
    int incl = v;
#pragma unroll
    for (int off = 1; off < 64; off <<= 1) {
      int u = __shfl_up(incl, off, 64);
      if (lane >= off) incl += u;
    }
    if (lane == 63) waveSums[wv] = incl;
    __syncthreads();
    if (wv == 0) {
      int s = (lane < 16) ? waveSums[lane] : 0;
#pragma unroll
      for (int off = 1; off < 16; off <<= 1) {
        int u = __shfl_up(s, off, 64);
        if (lane >= off) s += u;
      }
      if (lane < 16) waveSums[lane] = s;
    }
    __syncthreads();
    int waveOff = (wv == 0) ? 0 : waveSums[wv - 1];
    int excl = sCarry + waveOff + incl - v;
    if (i < N) offsets[i] = excl;
    __syncthreads();
    if (t == 0) sCarry += waveSums[15];
    __syncthreads();
  }
  if (t == 0) offsets[N] = sCarry;
}

__global__ void k_scatter(const int* __restrict__ src, const int* __restrict__ dst,
                          const float* __restrict__ ew, int* __restrict__ offsets,
                          int* __restrict__ csr_src, float* __restrict__ csr_w, int E) {
  int e = blockIdx.x * blockDim.x + threadIdx.x;
  if (e < E) {
    int p = atomicAdd(&offsets[dst[e]], 1);
    csr_src[p] = src[e];
    csr_w[p] = ew[e];
  }
}

// ---------- fused: gather-aggregate + expmap0/proj + relu(logmap0) + expmap0/proj ----------
__global__ __launch_bounds__(256) void k_agg_final(
    const float* __restrict__ xt, const int* __restrict__ csr_src,
    const float* __restrict__ csr_w, const int* __restrict__ offsets,
    const int* __restrict__ deg, float* __restrict__ out, int N) {
  int n = blockIdx.x * 4 + (threadIdx.x >> 6);
  int lane = threadIdx.x & 63;
  if (n >= N) return;
  int end = offsets[n];
  int dg = deg[n];
  int e = end - dg;
  float a0 = 0.f, a1 = 0.f;
  for (; e + 2 <= end; e += 2) {
    int s0 = csr_src[e], s1 = csr_src[e + 1];
    float w0 = csr_w[e], w1 = csr_w[e + 1];
    float2 u0 = ((const float2*)(xt + (size_t)s0 * 128))[lane];
    float2 u1 = ((const float2*)(xt + (size_t)s1 * 128))[lane];
    a0 = fmaf(w0, u0.x, a0);
    a1 = fmaf(w0, u0.y, a1);
    a0 = fmaf(w1, u1.x, a0);
    a1 = fmaf(w1, u1.y, a1);
  }
  if (e < end) {
    int s0 = csr_src[e];
    float w0 = csr_w[e];
    float2 u0 = ((const float2*)(xt + (size_t)s0 * 128))[lane];
    a0 = fmaf(w0, u0.x, a0);
    a1 = fmaf(w0, u0.y, a1);
  }
  float v0 = a0, v1 = a1;
  expmap0_proj(v0, v1);
  float nn = fmaxf(sqrtf(wave_sum(v0 * v0 + v1 * v1)), 1e-15f);
  float s = artanh_c(nn) / nn;
  v0 = fmaxf(v0 * s, 0.0f);
  v1 = fmaxf(v1 * s, 0.0f);
  expmap0_proj(v0, v1);
  ((float2*)(out + (size_t)n * 128))[lane] = make_float2(v0, v1);
}

// ---------- fallback path: edge atomics ----------
__global__ void k_edge(const float* __restrict__ xt, const float* __restrict__ ew,
                       const int* __restrict__ src, const int* __restrict__ dst,
                       float* __restrict__ agg, int E) {
  int tid = blockIdx.x * blockDim.x + threadIdx.x;
  int gw = tid >> 6;
  int lane = tid & 63;
  int nw = (gridDim.x * blockDim.x) >> 6;
  for (int e = gw; e < E; e += nw) {
    int s = src[e];
    int d = dst[e];
    float wgt = ew[e];
    float2 v = ((const float2*)(xt + (size_t)s * 128))[lane];
    float* base = agg + (size_t)d * 128 + 2 * lane;
    unsafeAtomicAdd(base, v.x * wgt);
    unsafeAtomicAdd(base + 1, v.y * wgt);
  }
}

__global__ void k_final(const float* __restrict__ agg, float* __restrict__ out, int N) {
  int gw = blockIdx.x * 4 + (threadIdx.x >> 6);
  int lane = threadIdx.x & 63;
  if (gw >= N) return;
  float2 v = ((const float2*)(agg + (size_t)gw * 128))[lane];
  float v0 = v.x, v1 = v.y;
  expmap0_proj(v0, v1);
  float n = fmaxf(sqrtf(wave_sum(v0 * v0 + v1 * v1)), 1e-15f);
  float s = artanh_c(n) / n;
  v0 = fmaxf(v0 * s, 0.0f);
  v1 = fmaxf(v1 * s, 0.0f);
  expmap0_proj(v0, v1);
  ((float2*)(out + (size_t)gw * 128))[lane] = make_float2(v0, v1);
}

static inline size_t pad256(size_t x) { return (x + 255) & ~(size_t)255; }

extern "C" void kernel_launch(void* const* d_in, const int* in_sizes, int n_in,
                              void* d_out, int out_size, void* d_ws, size_t ws_size,
                              hipStream_t stream) {
  const float* x = (const float*)d_in[0];
  const float* W = (const float*)d_in[1];
  const float* b = (const float*)d_in[2];
  const float* ew = (const float*)d_in[3];
  const int* src = (const int*)d_in[4];
  const int* dst = (const int*)d_in[5];
  float* out = (float*)d_out;
  const int N = in_sizes[0] / 128;
  const int E = in_sizes[3];

  char* p = (char*)d_ws;
  float* wsb = (float*)p;      p += 1024;
  int* deg = (int*)p;          p += pad256((size_t)N * 4);
  int* offsets = (int*)p;      p += pad256((size_t)(N + 1) * 4);
  int* csr_src = (int*)p;      p += pad256((size_t)E * 4);
  float* csr_w = (float*)p;    p += pad256((size_t)E * 4);
  float* xt = (float*)p;       p += (size_t)N * 512;
  size_t need = (size_t)(p - (char*)d_ws);

  if (ws_size >= need) {
    hipMemsetAsync(deg, 0, (size_t)N * 4, stream);
    k_bias<<<1, 64, 0, stream>>>(b, wsb);
    k_hist<<<(E + 255) / 256, 256, 0, stream>>>(dst, deg, E);
    k_scan<<<1, 1024, 0, stream>>>(deg, offsets, N);
    k_linear<<<(N + 63) / 64, 256, 0, stream>>>(x, W, wsb, xt, N);
    k_scatter<<<(E + 255) / 256, 256, 0, stream>>>(src, dst, ew, offsets, csr_src, csr_w, E);
    k_agg_final<<<(N + 3) / 4, 256, 0, stream>>>(xt, csr_src, csr_w, offsets, deg, out, N);
  } else {
    float* wsb2 = (float*)d_ws;
    float* agg = wsb2 + 256;
    hipMemsetAsync(agg, 0, (size_t)N * 128 * sizeof(float), stream);
    k_bias<<<1, 64, 0, stream>>>(b, wsb2);
    k_linear<<<(N + 63) / 64, 256, 0, stream>>>(x, W, wsb2, out, N);
    k_edge<<<2048, 256, 0, stream>>>(out, ew, src, dst, agg, E);
    k_final<<<(N + 3) / 4, 256, 0, stream>>>(agg, out, N);
  }
}

// Round 4
// 241.253 us; speedup vs baseline: 2.8442x; 1.0877x over previous
//
#include <hip/hip_runtime.h>
#include <math.h>

#define MAXNORM 0.996f  // (1 - 4e-3) / sqrt(c), c = 1

__device__ __forceinline__ float wave_sum(float v) {
#pragma unroll
  for (int off = 32; off > 0; off >>= 1) v += __shfl_xor(v, off, 64);
  return v;
}

__device__ __forceinline__ float artanh_c(float x) {
  x = fminf(fmaxf(x, -1.0f + 1e-7f), 1.0f - 1e-7f);
  return 0.5f * (log1pf(x) - log1pf(-x));
}

__device__ __forceinline__ void proj2(float& v0, float& v1) {
  float n = fmaxf(sqrtf(wave_sum(v0 * v0 + v1 * v1)), 1e-15f);
  if (n > MAXNORM) {
    float s = MAXNORM / n;
    v0 *= s;
    v1 *= s;
  }
}

__device__ __forceinline__ void expmap0_proj(float& v0, float& v1) {
  float n = fmaxf(sqrtf(wave_sum(v0 * v0 + v1 * v1)), 1e-15f);
  float s = tanhf(n) / n;
  v0 *= s;
  v1 *= s;
  proj2(v0, v1);
}

// ---------- K1: hyp_bias = proj(expmap0(b)) ; store bias + ||bias||^2 ----------
__global__ void k_bias(const float* __restrict__ b, float* __restrict__ wsb) {
  int lane = threadIdx.x;  // 64 threads
  float b0 = b[lane], b1 = b[lane + 64];
  float nb = fmaxf(sqrtf(wave_sum(b0 * b0 + b1 * b1)), 1e-15f);
  float s = tanhf(nb) / nb;
  float h0 = b0 * s, h1 = b1 * s;
  proj2(h0, h1);
  float y2 = wave_sum(h0 * h0 + h1 * h1);
  wsb[lane] = h0;
  wsb[lane + 64] = h1;
  if (lane == 0) wsb[128] = y2;
}

// ---------- K2: register-tiled GEMM (128 rows x 128 outs per block of 512) ----------
// Thread (tn = t&15, tm = t>>4): rows 4tm..4tm+3, cols 8tn..8tn+7, acc[4][8].
// W in LDS (64 KB, XOR-swizzled); x streamed from global (broadcast across tn lanes).
// 2 blocks/CU -> 4 waves/SIMD.
__global__ __launch_bounds__(512, 4) void k_linear(
    const float* __restrict__ x, const float* __restrict__ W,
    const float* __restrict__ wsb, float* __restrict__ xt, int N) {
  __shared__ float Ws[128 * 128];
  const int t = threadIdx.x;
  const int tn = t & 15;
  const int tm = t >> 4;  // 0..31

  // stage W: 4096 float4 / 512 threads = 8 each
  const float4* W4 = (const float4*)W;
#pragma unroll
  for (int i = 0; i < 8; ++i) {
    int idx = t + 512 * i;
    int row = idx >> 5;
    int col4 = (idx & 31) << 2;
    int sw = ((row >> 3) & 7) << 2;
    float4 v = W4[idx];
    *(float4*)&Ws[row * 128 + (col4 ^ sw)] = v;
  }

  float hb[8];
  *(float4*)&hb[0] = *(const float4*)&wsb[8 * tn];
  *(float4*)&hb[4] = *(const float4*)&wsb[8 * tn + 4];
  const float y2 = wsb[128];
  __syncthreads();

  const int tile0 = blockIdx.x * 128;
  const float4* X4 = (const float4*)x;
  int grow[4];
#pragma unroll
  for (int m = 0; m < 4; ++m) {
    int r = tile0 + 4 * tm + m;
    grow[m] = (r < N) ? r : (N - 1);  // clamp; stores are guarded
  }

  float acc[4][8];
#pragma unroll
  for (int m = 0; m < 4; ++m)
#pragma unroll
    for (int n = 0; n < 8; ++n) acc[m][n] = 0.f;
  float pxr[4] = {0.f, 0.f, 0.f, 0.f};

  const int sww = (tn & 7) << 2;
  const int wbase = (tn * 8) * 128;

#pragma unroll 2
  for (int kk = 0; kk < 32; ++kk) {
    const int k = kk << 2;
    float4 xf[4], wf[8];
#pragma unroll
    for (int m = 0; m < 4; ++m) xf[m] = X4[(size_t)grow[m] * 32 + kk];
#pragma unroll
    for (int n = 0; n < 8; ++n) wf[n] = *(const float4*)&Ws[wbase + n * 128 + (k ^ sww)];
#pragma unroll
    for (int m = 0; m < 4; ++m) {
      pxr[m] = fmaf(xf[m].x, xf[m].x, pxr[m]);
      pxr[m] = fmaf(xf[m].y, xf[m].y, pxr[m]);
      pxr[m] = fmaf(xf[m].z, xf[m].z, pxr[m]);
      pxr[m] = fmaf(xf[m].w, xf[m].w, pxr[m]);
#pragma unroll
      for (int n = 0; n < 8; ++n) {
        acc[m][n] = fmaf(xf[m].x, wf[n].x, acc[m][n]);
        acc[m][n] = fmaf(xf[m].y, wf[n].y, acc[m][n]);
        acc[m][n] = fmaf(xf[m].z, wf[n].z, acc[m][n]);
        acc[m][n] = fmaf(xf[m].w, wf[n].w, acc[m][n]);
      }
    }
  }

  // fused tail: per row r = 4tm+m — reductions over the 16-lane tn group
#pragma unroll
  for (int m = 0; m < 4; ++m) {
    const int growm = tile0 + 4 * tm + m;
    float pm = 0.f, pxy = 0.f;
#pragma unroll
    for (int n = 0; n < 8; ++n) {
      pm = fmaf(acc[m][n], acc[m][n], pm);
      pxy = fmaf(acc[m][n], hb[n], pxy);
    }
#pragma unroll
    for (int off = 1; off < 16; off <<= 1) {
      pm += __shfl_xor(pm, off, 64);
      pxy += __shfl_xor(pxy, off, 64);
    }
    float px = pxr[m];  // full-row ||x||^2, no reduction needed
    // scalar chain (uniform across the 16 tn lanes)
    float xn = fmaxf(sqrtf(px), 1e-15f);
    float mxn = fmaxf(sqrtf(pm), 1e-15f);
    float s1 = tanhf(mxn / xn * artanh_c(xn)) / mxn;
    if (pm == 0.0f) s1 = 0.0f;
    float nv = s1 * mxn;  // s1 >= 0
    if (nv > MAXNORM) {
      s1 *= MAXNORM / nv;
      nv = MAXNORM;
    }
    float x2 = nv * nv;
    float xy = s1 * pxy;
    float A = 1.0f + 2.0f * xy + y2;
    float B = 1.0f - x2;
    float den = fmaxf(1.0f + 2.0f * xy + x2 * y2, 1e-15f);
    float rn2 = fmaxf(A * A * x2 + 2.0f * A * B * xy + B * B * y2, 0.0f);
    float rn = sqrtf(rn2) / den;
    float g = 1.0f;
    if (rn > MAXNORM) g = MAXNORM / rn;
    float ng = fmaxf(fminf(rn, MAXNORM), 1e-15f);
    float slog = artanh_c(ng) / ng;
    float ftot = slog * g / den;
    float f1 = ftot * A * s1;
    float f2 = ftot * B;
    if (growm < N) {
      float o[8];
#pragma unroll
      for (int n = 0; n < 8; ++n) o[n] = f1 * acc[m][n] + f2 * hb[n];
      *(float4*)&xt[(size_t)growm * 128 + 8 * tn] = make_float4(o[0], o[1], o[2], o[3]);
      *(float4*)&xt[(size_t)growm * 128 + 8 * tn + 4] = make_float4(o[4], o[5], o[6], o[7]);
    }
  }
}

// ---------- CSR build ----------
__global__ void k_hist(const int* __restrict__ dst, int* __restrict__ deg, int E) {
  int e = blockIdx.x * blockDim.x + threadIdx.x;
  if (e < E) atomicAdd(&deg[dst[e]], 1);
}

__global__ __launch_bounds__(1024) void k_scan(const int* __restrict__ deg,
                                               int* __restrict__ offsets, int N) {
  __shared__ int waveSums[16];
  __shared__ int sCarry;
  int t = threadIdx.x;
  int lane = t & 63, wv = t >> 6;
  if (t == 0) sCarry = 0;
  __syncthreads();
  for (int base = 0; base < N; base += 1024) {
    int i = base + t;
    int v = (i < N) ? deg[i] : 0;
    int incl = v;
#pragma unroll
    for (int off = 1; off < 64; off <<= 1) {
      int u = __shfl_up(incl, off, 64);
      if (lane >= off) incl += u;
    }
    if (lane == 63) waveSums[wv] = incl;
    __syncthreads();
    if (wv == 0) {
      int s = (lane < 16) ? waveSums[lane] : 0;
#pragma unroll
      for (int off = 1; off < 16; off <<= 1) {
        int u = __shfl_up(s, off, 64);
        if (lane >= off) s += u;
      }
      if (lane < 16) waveSums[lane] = s;
    }
    __syncthreads();
    int waveOff = (wv == 0) ? 0 : waveSums[wv - 1];
    int excl = sCarry + waveOff + incl - v;
    if (i < N) offsets[i] = excl;
    __syncthreads();
    if (t == 0) sCarry += waveSums[15];
    __syncthreads();
  }
  if (t == 0) offsets[N] = sCarry;
}

__global__ void k_scatter(const int* __restrict__ src, const int* __restrict__ dst,
                          const float* __restrict__ ew, int* __restrict__ offsets,
                          int* __restrict__ csr_src, float* __restrict__ csr_w, int E) {
  int e = blockIdx.x * blockDim.x + threadIdx.x;
  if (e < E) {
    int p = atomicAdd(&offsets[dst[e]], 1);
    csr_src[p] = src[e];
    csr_w[p] = ew[e];
  }
}

// ---------- fused: gather-aggregate + expmap0/proj + relu(logmap0) + expmap0/proj ----------
__global__ __launch_bounds__(256) void k_agg_final(
    const float* __restrict__ xt, const int* __restrict__ csr_src,
    const float* __restrict__ csr_w, const int* __restrict__ offsets,
    const int* __restrict__ deg, float* __restrict__ out, int N) {
  int n = blockIdx.x * 4 + (threadIdx.x >> 6);
  int lane = threadIdx.x & 63;
  if (n >= N) return;
  int end = offsets[n];
  int dg = deg[n];
  int e = end - dg;
  float a0 = 0.f, a1 = 0.f;
  for (; e + 2 <= end; e += 2) {
    int s0 = csr_src[e], s1 = csr_src[e + 1];
    float w0 = csr_w[e], w1 = csr_w[e + 1];
    float2 u0 = ((const float2*)(xt + (size_t)s0 * 128))[lane];
    float2 u1 = ((const float2*)(xt + (size_t)s1 * 128))[lane];
    a0 = fmaf(w0, u0.x, a0);
    a1 = fmaf(w0, u0.y, a1);
    a0 = fmaf(w1, u1.x, a0);
    a1 = fmaf(w1, u1.y, a1);
  }
  if (e < end) {
    int s0 = csr_src[e];
    float w0 = csr_w[e];
    float2 u0 = ((const float2*)(xt + (size_t)s0 * 128))[lane];
    a0 = fmaf(w0, u0.x, a0);
    a1 = fmaf(w0, u0.y, a1);
  }
  float v0 = a0, v1 = a1;
  expmap0_proj(v0, v1);
  float nn = fmaxf(sqrtf(wave_sum(v0 * v0 + v1 * v1)), 1e-15f);
  float s = artanh_c(nn) / nn;
  v0 = fmaxf(v0 * s, 0.0f);
  v1 = fmaxf(v1 * s, 0.0f);
  expmap0_proj(v0, v1);
  ((float2*)(out + (size_t)n * 128))[lane] = make_float2(v0, v1);
}

// ---------- fallback path: edge atomics ----------
__global__ void k_edge(const float* __restrict__ xt, const float* __restrict__ ew,
                       const int* __restrict__ src, const int* __restrict__ dst,
                       float* __restrict__ agg, int E) {
  int tid = blockIdx.x * blockDim.x + threadIdx.x;
  int gw = tid >> 6;
  int lane = tid & 63;
  int nw = (gridDim.x * blockDim.x) >> 6;
  for (int e = gw; e < E; e += nw) {
    int s = src[e];
    int d = dst[e];
    float wgt = ew[e];
    float2 v = ((const float2*)(xt + (size_t)s * 128))[lane];
    float* base = agg + (size_t)d * 128 + 2 * lane;
    unsafeAtomicAdd(base, v.x * wgt);
    unsafeAtomicAdd(base + 1, v.y * wgt);
  }
}

__global__ void k_final(const float* __restrict__ agg, float* __restrict__ out, int N) {
  int gw = blockIdx.x * 4 + (threadIdx.x >> 6);
  int lane = threadIdx.x & 63;
  if (gw >= N) return;
  float2 v = ((const float2*)(agg + (size_t)gw * 128))[lane];
  float v0 = v.x, v1 = v.y;
  expmap0_proj(v0, v1);
  float n = fmaxf(sqrtf(wave_sum(v0 * v0 + v1 * v1)), 1e-15f);
  float s = artanh_c(n) / n;
  v0 = fmaxf(v0 * s, 0.0f);
  v1 = fmaxf(v1 * s, 0.0f);
  expmap0_proj(v0, v1);
  ((float2*)(out + (size_t)gw * 128))[lane] = make_float2(v0, v1);
}

static inline size_t pad256(size_t x) { return (x + 255) & ~(size_t)255; }

extern "C" void kernel_launch(void* const* d_in, const int* in_sizes, int n_in,
                              void* d_out, int out_size, void* d_ws, size_t ws_size,
                              hipStream_t stream) {
  const float* x = (const float*)d_in[0];
  const float* W = (const float*)d_in[1];
  const float* b = (const float*)d_in[2];
  const float* ew = (const float*)d_in[3];
  const int* src = (const int*)d_in[4];
  const int* dst = (const int*)d_in[5];
  float* out = (float*)d_out;
  const int N = in_sizes[0] / 128;
  const int E = in_sizes[3];

  char* p = (char*)d_ws;
  float* wsb = (float*)p;      p += 1024;
  int* deg = (int*)p;          p += pad256((size_t)N * 4);
  int* offsets = (int*)p;      p += pad256((size_t)(N + 1) * 4);
  int* csr_src = (int*)p;      p += pad256((size_t)E * 4);
  float* csr_w = (float*)p;    p += pad256((size_t)E * 4);
  float* xt = (float*)p;       p += (size_t)N * 512;
  size_t need = (size_t)(p - (char*)d_ws);

  if (ws_size >= need) {
    hipMemsetAsync(deg, 0, (size_t)N * 4, stream);
    k_bias<<<1, 64, 0, stream>>>(b, wsb);
    k_hist<<<(E + 255) / 256, 256, 0, stream>>>(dst, deg, E);
    k_scan<<<1, 1024, 0, stream>>>(deg, offsets, N);
    k_linear<<<(N + 127) / 128, 512, 0, stream>>>(x, W, wsb, xt, N);
    k_scatter<<<(E + 255) / 256, 256, 0, stream>>>(src, dst, ew, offsets, csr_src, csr_w, E);
    k_agg_final<<<(N + 3) / 4, 256, 0, stream>>>(xt, csr_src, csr_w, offsets, deg, out, N);
  } else {
    float* wsb2 = (float*)d_ws;
    float* agg = wsb2 + 256;
    hipMemsetAsync(agg, 0, (size_t)N * 128 * sizeof(float), stream);
    k_bias<<<1, 64, 0, stream>>>(b, wsb2);
    k_linear<<<(N + 127) / 128, 512, 0, stream>>>(x, W, wsb2, out, N);
    k_edge<<<2048, 256, 0, stream>>>(out, ew, src, dst, agg, E);
    k_final<<<(N + 3) / 4, 256, 0, stream>>>(agg, out, N);
  }
}

// Round 6
// 187.779 us; speedup vs baseline: 3.6542x; 1.2848x over previous
//
#include <hip/hip_runtime.h>
#include <math.h>

#define MAXNORM 0.996f  // (1 - 4e-3) / sqrt(c), c = 1

typedef _Float16 h2 __attribute__((ext_vector_type(2)));
typedef _Float16 h4 __attribute__((ext_vector_type(4)));
typedef _Float16 h8 __attribute__((ext_vector_type(8)));

#if defined(__has_builtin)
#if __has_builtin(__builtin_amdgcn_fdot2)
#define HAS_FDOT2 1
#endif
#endif

__device__ __forceinline__ float dot2acc(h2 a, h2 b, float c) {
#ifdef HAS_FDOT2
  return __builtin_amdgcn_fdot2(a, b, c, false);
#else
  return fmaf((float)a[0], (float)b[0], fmaf((float)a[1], (float)b[1], c));
#endif
}

__device__ __forceinline__ h2 pack2(float lo, float hi) {
  return __builtin_bit_cast(h2, __builtin_amdgcn_cvt_pkrtz(lo, hi));
}

__device__ __forceinline__ float wave_sum(float v) {
#pragma unroll
  for (int off = 32; off > 0; off >>= 1) v += __shfl_xor(v, off, 64);
  return v;
}

__device__ __forceinline__ float artanh_c(float x) {
  x = fminf(fmaxf(x, -1.0f + 1e-7f), 1.0f - 1e-7f);
  return 0.5f * (log1pf(x) - log1pf(-x));
}

__device__ __forceinline__ void proj2(float& v0, float& v1) {
  float n = fmaxf(sqrtf(wave_sum(v0 * v0 + v1 * v1)), 1e-15f);
  if (n > MAXNORM) {
    float s = MAXNORM / n;
    v0 *= s;
    v1 *= s;
  }
}

__device__ __forceinline__ void expmap0_proj(float& v0, float& v1) {
  float n = fmaxf(sqrtf(wave_sum(v0 * v0 + v1 * v1)), 1e-15f);
  float s = tanhf(n) / n;
  v0 *= s;
  v1 *= s;
  proj2(v0, v1);
}

// ---------- K1: hyp_bias = proj(expmap0(b)) ; store bias + ||bias||^2 ----------
__global__ void k_bias(const float* __restrict__ b, float* __restrict__ wsb) {
  int lane = threadIdx.x;  // 64 threads
  float b0 = b[lane], b1 = b[lane + 64];
  float nb = fmaxf(sqrtf(wave_sum(b0 * b0 + b1 * b1)), 1e-15f);
  float s = tanhf(nb) / nb;
  float h0 = b0 * s, h1 = b1 * s;
  proj2(h0, h1);
  float y2 = wave_sum(h0 * h0 + h1 * h1);
  wsb[lane] = h0;
  wsb[lane + 64] = h1;
  if (lane == 0) wsb[128] = y2;
}

// ---------- K2: fp16 register-tiled GEMM (64 rows x 128 outs, 256 thr) ----------
// Thread (tn = t&15, tm = t>>4): rows 4tm..4tm+3, cols 8tn..8tn+7, f32 acc[4][8].
// W staged fp16 in LDS (32 KB, XOR-swizzled); x streamed f32 from global,
// packed to h2; inner product via v_dot2_f32_f16. 4 blocks/CU.
__global__ __launch_bounds__(256, 4) void k_linear(
    const float* __restrict__ x, const float* __restrict__ W,
    const float* __restrict__ wsb, h2* __restrict__ xt, int N) {
  __shared__ h2 WsH[128 * 64];
  const int t = threadIdx.x;
  const int tn = t & 15;
  const int tm = t >> 4;  // 0..15

  // stage W (f32 -> f16 RTZ): 4096 float4 / 256 thr = 16 each
  const float4* W4 = (const float4*)W;
#pragma unroll
  for (int i = 0; i < 16; ++i) {
    int f = t + 256 * i;
    int row = f >> 5;      // 32 float4 per row
    int p = (f & 31) * 2;  // h2 index within row
    int sw = ((row >> 3) & 7) << 2;
    float4 v = W4[f];
    h4 hv;
    h2 lo = pack2(v.x, v.y);
    h2 hi = pack2(v.z, v.w);
    hv[0] = lo[0];
    hv[1] = lo[1];
    hv[2] = hi[0];
    hv[3] = hi[1];
    *(h4*)&WsH[row * 64 + (p ^ sw)] = hv;
  }

  float hb[8];
  *(float4*)&hb[0] = *(const float4*)&wsb[8 * tn];
  *(float4*)&hb[4] = *(const float4*)&wsb[8 * tn + 4];
  const float y2 = wsb[128];
  __syncthreads();

  const int tile0 = blockIdx.x * 64;
  const float4* X4 = (const float4*)x;
  int grow[4];
#pragma unroll
  for (int m = 0; m < 4; ++m) {
    int r = tile0 + 4 * tm + m;
    grow[m] = (r < N) ? r : (N - 1);  // clamp; stores guarded
  }

  float acc[4][8];
#pragma unroll
  for (int m = 0; m < 4; ++m)
#pragma unroll
    for (int n = 0; n < 8; ++n) acc[m][n] = 0.f;
  float pxr[4] = {0.f, 0.f, 0.f, 0.f};

  const int sww = (tn & 7) << 2;

#pragma unroll 2
  for (int kk = 0; kk < 16; ++kk) {  // K-step = 8 floats
    h2 xh[4][4];
#pragma unroll
    for (int m = 0; m < 4; ++m) {
      float4 a = X4[(size_t)grow[m] * 32 + 2 * kk];
      float4 c = X4[(size_t)grow[m] * 32 + 2 * kk + 1];
      pxr[m] = fmaf(a.x, a.x, pxr[m]);
      pxr[m] = fmaf(a.y, a.y, pxr[m]);
      pxr[m] = fmaf(a.z, a.z, pxr[m]);
      pxr[m] = fmaf(a.w, a.w, pxr[m]);
      pxr[m] = fmaf(c.x, c.x, pxr[m]);
      pxr[m] = fmaf(c.y, c.y, pxr[m]);
      pxr[m] = fmaf(c.z, c.z, pxr[m]);
      pxr[m] = fmaf(c.w, c.w, pxr[m]);
      xh[m][0] = pack2(a.x, a.y);
      xh[m][1] = pack2(a.z, a.w);
      xh[m][2] = pack2(c.x, c.y);
      xh[m][3] = pack2(c.z, c.w);
    }
    const int k2 = kk * 4;
#pragma unroll
    for (int n = 0; n < 8; ++n) {
      const h8 w = *(const h8*)&WsH[(tn * 8 + n) * 64 + (k2 ^ sww)];
      h2 w0 = __builtin_shufflevector(w, w, 0, 1);
      h2 w1 = __builtin_shufflevector(w, w, 2, 3);
      h2 w2 = __builtin_shufflevector(w, w, 4, 5);
      h2 w3 = __builtin_shufflevector(w, w, 6, 7);
#pragma unroll
      for (int m = 0; m < 4; ++m) {
        acc[m][n] = dot2acc(xh[m][0], w0, acc[m][n]);
        acc[m][n] = dot2acc(xh[m][1], w1, acc[m][n]);
        acc[m][n] = dot2acc(xh[m][2], w2, acc[m][n]);
        acc[m][n] = dot2acc(xh[m][3], w3, acc[m][n]);
      }
    }
  }

  // fused tail: per row — reductions over the 16-lane tn group
#pragma unroll
  for (int m = 0; m < 4; ++m) {
    const int growm = tile0 + 4 * tm + m;
    float pm = 0.f, pxy = 0.f;
#pragma unroll
    for (int n = 0; n < 8; ++n) {
      pm = fmaf(acc[m][n], acc[m][n], pm);
      pxy = fmaf(acc[m][n], hb[n], pxy);
    }
#pragma unroll
    for (int off = 1; off < 16; off <<= 1) {
      pm += __shfl_xor(pm, off, 64);
      pxy += __shfl_xor(pxy, off, 64);
    }
    float px = pxr[m];
    float xn = fmaxf(sqrtf(px), 1e-15f);
    float mxn = fmaxf(sqrtf(pm), 1e-15f);
    float s1 = tanhf(mxn / xn * artanh_c(xn)) / mxn;
    if (pm == 0.0f) s1 = 0.0f;
    float nv = s1 * mxn;
    if (nv > MAXNORM) {
      s1 *= MAXNORM / nv;
      nv = MAXNORM;
    }
    float x2 = nv * nv;
    float xy = s1 * pxy;
    float A = 1.0f + 2.0f * xy + y2;
    float B = 1.0f - x2;
    float den = fmaxf(1.0f + 2.0f * xy + x2 * y2, 1e-15f);
    float rn2 = fmaxf(A * A * x2 + 2.0f * A * B * xy + B * B * y2, 0.0f);
    float rn = sqrtf(rn2) / den;
    float g = 1.0f;
    if (rn > MAXNORM) g = MAXNORM / rn;
    float ng = fmaxf(fminf(rn, MAXNORM), 1e-15f);
    float slog = artanh_c(ng) / ng;
    float ftot = slog * g / den;
    float f1 = ftot * A * s1;
    float f2 = ftot * B;
    if (growm < N) {
      h8 ov;
#pragma unroll
      for (int n = 0; n < 8; ++n) ov[n] = (_Float16)(f1 * acc[m][n] + f2 * hb[n]);
      *(h8*)&xt[(size_t)growm * 64 + 4 * tn] = ov;
    }
  }
}

// ---------- CSR build ----------
__global__ void k_hist(const int* __restrict__ dst, int* __restrict__ deg, int E) {
  int e = blockIdx.x * blockDim.x + threadIdx.x;
  if (e < E) atomicAdd(&deg[dst[e]], 1);
}

// single-block exclusive scan, int4-vectorized
__global__ __launch_bounds__(1024) void k_scan(const int* __restrict__ deg,
                                               int* __restrict__ offsets, int N) {
  __shared__ int waveSums[16];
  __shared__ int sCarry;
  const int t = threadIdx.x;
  const int lane = t & 63, wv = t >> 6;
  const int N4 = N >> 2;
  const int4* deg4 = (const int4*)deg;
  if (t == 0) sCarry = 0;
  __syncthreads();
  for (int base = 0; base < N4; base += 1024) {
    int i = base + t;
    int4 v = (i < N4) ? deg4[i] : make_int4(0, 0, 0, 0);
    int s0 = v.x, s1 = s0 + v.y, s2 = s1 + v.z, s3 = s2 + v.w;
    int incl = s3;
#pragma unroll
    for (int off = 1; off < 64; off <<= 1) {
      int u = __shfl_up(incl, off, 64);
      if (lane >= off) incl += u;
    }
    if (lane == 63) waveSums[wv] = incl;
    __syncthreads();
    if (wv == 0) {
      int s = (lane < 16) ? waveSums[lane] : 0;
#pragma unroll
      for (int off = 1; off < 16; off <<= 1) {
        int u = __shfl_up(s, off, 64);
        if (lane >= off) s += u;
      }
      if (lane < 16) waveSums[lane] = s;
    }
    __syncthreads();
    int C = sCarry + ((wv == 0) ? 0 : waveSums[wv - 1]) + (incl - s3);
    if (i < N4) ((int4*)offsets)[i] = make_int4(C, C + s0, C + s1, C + s2);
    __syncthreads();
    if (t == 0) sCarry += waveSums[15];
    __syncthreads();
  }
  if (t == 0) {
    int total = sCarry;
    for (int j = N4 << 2; j < N; ++j) {
      offsets[j] = total;
      total += deg[j];
    }
    offsets[N] = total;
  }
}

// scatter edges into CSR (packed {src, weight} in one 8B store)
__global__ void k_scatter(const int* __restrict__ src, const int* __restrict__ dst,
                          const float* __restrict__ ew, int* __restrict__ offsets,
                          uint2* __restrict__ csr, int E) {
  int e = blockIdx.x * blockDim.x + threadIdx.x;
  if (e < E) {
    int p = atomicAdd(&offsets[dst[e]], 1);
    csr[p] = make_uint2((unsigned)src[e], __float_as_uint(ew[e]));
  }
}

// ---------- fused: gather-aggregate (fp16 xt) + expmap/relu/expmap tail ----------
__global__ __launch_bounds__(256) void k_agg_final(
    const h2* __restrict__ xt, const uint2* __restrict__ csr,
    const int* __restrict__ offsets, const int* __restrict__ deg,
    float* __restrict__ out, int N) {
  int n = blockIdx.x * 4 + (threadIdx.x >> 6);
  int lane = threadIdx.x & 63;
  if (n >= N) return;
  int end = offsets[n];  // post-scatter: end of segment
  int e = end - deg[n];
  float a0 = 0.f, a1 = 0.f;
  for (; e + 4 <= end; e += 4) {
    uint2 c0 = csr[e], c1 = csr[e + 1], c2 = csr[e + 2], c3 = csr[e + 3];
    h2 u0 = xt[(size_t)c0.x * 64 + lane];
    h2 u1 = xt[(size_t)c1.x * 64 + lane];
    h2 u2 = xt[(size_t)c2.x * 64 + lane];
    h2 u3 = xt[(size_t)c3.x * 64 + lane];
    float w0 = __uint_as_float(c0.y), w1 = __uint_as_float(c1.y);
    float w2 = __uint_as_float(c2.y), w3 = __uint_as_float(c3.y);
    a0 = fmaf(w0, (float)u0[0], a0);
    a1 = fmaf(w0, (float)u0[1], a1);
    a0 = fmaf(w1, (float)u1[0], a0);
    a1 = fmaf(w1, (float)u1[1], a1);
    a0 = fmaf(w2, (float)u2[0], a0);
    a1 = fmaf(w2, (float)u2[1], a1);
    a0 = fmaf(w3, (float)u3[0], a0);
    a1 = fmaf(w3, (float)u3[1], a1);
  }
  for (; e < end; ++e) {
    uint2 c0 = csr[e];
    h2 u0 = xt[(size_t)c0.x * 64 + lane];
    float w0 = __uint_as_float(c0.y);
    a0 = fmaf(w0, (float)u0[0], a0);
    a1 = fmaf(w0, (float)u0[1], a1);
  }
  float v0 = a0, v1 = a1;
  expmap0_proj(v0, v1);
  float nn = fmaxf(sqrtf(wave_sum(v0 * v0 + v1 * v1)), 1e-15f);
  float s = artanh_c(nn) / nn;
  v0 = fmaxf(v0 * s, 0.0f);
  v1 = fmaxf(v1 * s, 0.0f);
  expmap0_proj(v0, v1);
  ((float2*)(out + (size_t)n * 128))[lane] = make_float2(v0, v1);
}

// ---------- fallback path: edge atomics (fp16 xt) ----------
__global__ void k_edge(const h2* __restrict__ xt, const float* __restrict__ ew,
                       const int* __restrict__ src, const int* __restrict__ dst,
                       float* __restrict__ agg, int E) {
  int tid = blockIdx.x * blockDim.x + threadIdx.x;
  int gw = tid >> 6;
  int lane = tid & 63;
  int nw = (gridDim.x * blockDim.x) >> 6;
  for (int e = gw; e < E; e += nw) {
    int s = src[e];
    int d = dst[e];
    float wgt = ew[e];
    h2 v = xt[(size_t)s * 64 + lane];
    float* base = agg + (size_t)d * 128 + 2 * lane;
    unsafeAtomicAdd(base, (float)v[0] * wgt);
    unsafeAtomicAdd(base + 1, (float)v[1] * wgt);
  }
}

__global__ void k_final(const float* __restrict__ agg, float* __restrict__ out, int N) {
  int gw = blockIdx.x * 4 + (threadIdx.x >> 6);
  int lane = threadIdx.x & 63;
  if (gw >= N) return;
  float2 v = ((const float2*)(agg + (size_t)gw * 128))[lane];
  float v0 = v.x, v1 = v.y;
  expmap0_proj(v0, v1);
  float n = fmaxf(sqrtf(wave_sum(v0 * v0 + v1 * v1)), 1e-15f);
  float s = artanh_c(n) / n;
  v0 = fmaxf(v0 * s, 0.0f);
  v1 = fmaxf(v1 * s, 0.0f);
  expmap0_proj(v0, v1);
  ((float2*)(out + (size_t)gw * 128))[lane] = make_float2(v0, v1);
}

static inline size_t pad256(size_t x) { return (x + 255) & ~(size_t)255; }

extern "C" void kernel_launch(void* const* d_in, const int* in_sizes, int n_in,
                              void* d_out, int out_size, void* d_ws, size_t ws_size,
                              hipStream_t stream) {
  const float* x = (const float*)d_in[0];
  const float* W = (const float*)d_in[1];
  const float* b = (const float*)d_in[2];
  const float* ew = (const float*)d_in[3];
  const int* src = (const int*)d_in[4];
  const int* dst = (const int*)d_in[5];
  float* out = (float*)d_out;
  const int N = in_sizes[0] / 128;
  const int E = in_sizes[3];

  char* p = (char*)d_ws;
  float* wsb = (float*)p;    p += 1024;
  int* deg = (int*)p;        p += pad256((size_t)N * 4);
  int* offsets = (int*)p;    p += pad256((size_t)(N + 1) * 4);
  uint2* csr = (uint2*)p;    p += pad256((size_t)E * 8);
  h2* xt = (h2*)p;           p += (size_t)N * 256;  // N*128 halfs
  size_t need = (size_t)(p - (char*)d_ws);

  if (ws_size >= need) {
    (void)hipMemsetAsync(deg, 0, (size_t)N * 4, stream);
    k_bias<<<1, 64, 0, stream>>>(b, wsb);
    k_hist<<<(E + 255) / 256, 256, 0, stream>>>(dst, deg, E);
    k_scan<<<1, 1024, 0, stream>>>(deg, offsets, N);
    k_linear<<<(N + 63) / 64, 256, 0, stream>>>(x, W, wsb, xt, N);
    k_scatter<<<(E + 255) / 256, 256, 0, stream>>>(src, dst, ew, offsets, csr, E);
    k_agg_final<<<(N + 3) / 4, 256, 0, stream>>>(xt, csr, offsets, deg, out, N);
  } else {
    float* wsb2 = (float*)d_ws;
    float* agg = wsb2 + 256;
    h2* xth = (h2*)d_out;  // first 12.8 MB of out reused as fp16 xt staging
    (void)hipMemsetAsync(agg, 0, (size_t)N * 128 * sizeof(float), stream);
    k_bias<<<1, 64, 0, stream>>>(b, wsb2);
    k_linear<<<(N + 63) / 64, 256, 0, stream>>>(x, W, wsb2, xth, N);
    k_edge<<<2048, 256, 0, stream>>>(xth, ew, src, dst, agg, E);
    k_final<<<(N + 3) / 4, 256, 0, stream>>>(agg, out, N);
  }
}

// Round 7
// 160.795 us; speedup vs baseline: 4.2674x; 1.1678x over previous
//
#include <hip/hip_runtime.h>
#include <math.h>

#define MAXNORM 0.996f  // (1 - 4e-3) / sqrt(c), c = 1

typedef _Float16 h2 __attribute__((ext_vector_type(2)));
typedef _Float16 h8v __attribute__((ext_vector_type(8)));
typedef float f4v __attribute__((ext_vector_type(4)));

__device__ __forceinline__ float wave_sum(float v) {
#pragma unroll
  for (int off = 32; off > 0; off >>= 1) v += __shfl_xor(v, off, 64);
  return v;
}

__device__ __forceinline__ float artanh_c(float x) {
  x = fminf(fmaxf(x, -1.0f + 1e-7f), 1.0f - 1e-7f);
  return 0.5f * (log1pf(x) - log1pf(-x));
}

__device__ __forceinline__ void proj2(float& v0, float& v1) {
  float n = fmaxf(sqrtf(wave_sum(v0 * v0 + v1 * v1)), 1e-15f);
  if (n > MAXNORM) {
    float s = MAXNORM / n;
    v0 *= s;
    v1 *= s;
  }
}

__device__ __forceinline__ void expmap0_proj(float& v0, float& v1) {
  float n = fmaxf(sqrtf(wave_sum(v0 * v0 + v1 * v1)), 1e-15f);
  float s = tanhf(n) / n;
  v0 *= s;
  v1 *= s;
  proj2(v0, v1);
}

// ---------- K1: hyp_bias = proj(expmap0(b)) ; store bias + ||bias||^2 ----------
__global__ void k_bias(const float* __restrict__ b, float* __restrict__ wsb) {
  int lane = threadIdx.x;  // 64 threads
  float b0 = b[lane], b1 = b[lane + 64];
  float nb = fmaxf(sqrtf(wave_sum(b0 * b0 + b1 * b1)), 1e-15f);
  float s = tanhf(nb) / nb;
  float h0 = b0 * s, h1 = b1 * s;
  proj2(h0, h1);
  float y2 = wave_sum(h0 * h0 + h1 * h1);
  wsb[lane] = h0;
  wsb[lane + 64] = h1;
  if (lane == 0) wsb[128] = y2;
}

// ---------- K2: MFMA GEMM (64 rows/block, 4 waves, 16-row stripe per wave) ----------
// mfma_f32_16x16x32_f16. A (x): lane row=lane&15, k=(lane>>4)*8+j (from global).
// B (W^T): lane col=lane&15, k=(lane>>4)*8+j (from LDS fp16, XOR-swizzled).
// D: col(o)=lane&15, row(i)=(lane>>4)*4+reg.
__global__ __launch_bounds__(256, 4) void k_linear(
    const float* __restrict__ x, const float* __restrict__ W,
    const float* __restrict__ wsb, _Float16* __restrict__ xt, int N) {
  __shared__ _Float16 WsH[128 * 128];  // 32 KB
  const int t = threadIdx.x;
  const int lane = t & 63;
  const int wv = t >> 6;

  // stage W fp16, swizzle h-index: k ^= (o&7)<<3
  const float4* W4 = (const float4*)W;
#pragma unroll
  for (int i = 0; i < 16; ++i) {
    int f = t + 256 * i;   // 4096 float4 total
    int o = f >> 5;
    int k4 = (f & 31) << 2;
    float4 v = W4[f];
    unsigned lo = __builtin_bit_cast(unsigned, __builtin_amdgcn_cvt_pkrtz(v.x, v.y));
    unsigned hi = __builtin_bit_cast(unsigned, __builtin_amdgcn_cvt_pkrtz(v.z, v.w));
    *(uint2*)&WsH[o * 128 + (k4 ^ ((o & 7) << 3))] = make_uint2(lo, hi);
  }

  const int col = lane & 15;  // o within tile; also A-row within stripe
  const int g = lane >> 4;    // k-group 0..3
  float hbv[8];
#pragma unroll
  for (int n = 0; n < 8; ++n) hbv[n] = wsb[col + 16 * n];
  const float y2 = wsb[128];
  __syncthreads();

  const int stripe0 = blockIdx.x * 64 + wv * 16;
  int arow = stripe0 + col;
  if (arow >= N) arow = N - 1;  // clamp; stores guarded
  const float4* X4 = (const float4*)x;

  // A fragments for 4 K-steps + in-register ||x_row||^2
  h8v af[4];
  float pxr = 0.f;
#pragma unroll
  for (int s = 0; s < 4; ++s) {
    float4 a = X4[(size_t)arow * 32 + 8 * s + 2 * g];
    float4 c = X4[(size_t)arow * 32 + 8 * s + 2 * g + 1];
    pxr = fmaf(a.x, a.x, pxr);
    pxr = fmaf(a.y, a.y, pxr);
    pxr = fmaf(a.z, a.z, pxr);
    pxr = fmaf(a.w, a.w, pxr);
    pxr = fmaf(c.x, c.x, pxr);
    pxr = fmaf(c.y, c.y, pxr);
    pxr = fmaf(c.z, c.z, pxr);
    pxr = fmaf(c.w, c.w, pxr);
    union {
      uint4 u;
      h8v h;
    } cv;
    cv.u = make_uint4(
        __builtin_bit_cast(unsigned, __builtin_amdgcn_cvt_pkrtz(a.x, a.y)),
        __builtin_bit_cast(unsigned, __builtin_amdgcn_cvt_pkrtz(a.z, a.w)),
        __builtin_bit_cast(unsigned, __builtin_amdgcn_cvt_pkrtz(c.x, c.y)),
        __builtin_bit_cast(unsigned, __builtin_amdgcn_cvt_pkrtz(c.z, c.w)));
    af[s] = cv.h;
  }
  // rows are partitioned 4-ways across g: full reduce
  pxr += __shfl_xor(pxr, 16, 64);
  pxr += __shfl_xor(pxr, 32, 64);
  // now lane i (i<16) holds ||x_{stripe0+i}||^2

  f4v acc[8];
  const f4v zero = {0.f, 0.f, 0.f, 0.f};
#pragma unroll
  for (int n = 0; n < 8; ++n) acc[n] = zero;

  const int osw = (col & 7) << 3;  // (o&7) == (col&7) since o = 16n + col
#pragma unroll
  for (int n = 0; n < 8; ++n) {
    const int obase = (16 * n + col) * 128;
#pragma unroll
    for (int s = 0; s < 4; ++s) {
      h8v bf = *(const h8v*)&WsH[obase + ((32 * s + 8 * g) ^ osw)];
      acc[n] = __builtin_amdgcn_mfma_f32_16x16x32_f16(af[s], bf, acc[n], 0, 0, 0);
    }
  }

  // fused HypLinear tail; D row i = g*4 + r, o = col + 16n
#pragma unroll
  for (int r = 0; r < 4; ++r) {
    float pm = 0.f, pxy = 0.f;
#pragma unroll
    for (int n = 0; n < 8; ++n) {
      float v = acc[n][r];
      pm = fmaf(v, v, pm);
      pxy = fmaf(v, hbv[n], pxy);
    }
#pragma unroll
    for (int off = 1; off < 16; off <<= 1) {
      pm += __shfl_xor(pm, off, 64);
      pxy += __shfl_xor(pxy, off, 64);
    }
    const int irow = g * 4 + r;
    float px = __shfl(pxr, irow, 64);
    // scalar chain (uniform across the 16 lanes of the o-group)
    float xn = fmaxf(sqrtf(px), 1e-15f);
    float mxn = fmaxf(sqrtf(pm), 1e-15f);
    float s1 = tanhf(mxn / xn * artanh_c(xn)) / mxn;
    if (pm == 0.0f) s1 = 0.0f;
    float nv = s1 * mxn;
    if (nv > MAXNORM) {
      s1 *= MAXNORM / nv;
      nv = MAXNORM;
    }
    float x2 = nv * nv;
    float xy = s1 * pxy;
    float A = 1.0f + 2.0f * xy + y2;
    float B = 1.0f - x2;
    float den = fmaxf(1.0f + 2.0f * xy + x2 * y2, 1e-15f);
    float rn2 = fmaxf(A * A * x2 + 2.0f * A * B * xy + B * B * y2, 0.0f);
    float rn = sqrtf(rn2) / den;
    float gs = 1.0f;
    if (rn > MAXNORM) gs = MAXNORM / rn;
    float ng = fmaxf(fminf(rn, MAXNORM), 1e-15f);
    float slog = artanh_c(ng) / ng;
    float ftot = slog * gs / den;
    float f1 = ftot * A * s1;
    float f2 = ftot * B;
    const int growm = stripe0 + irow;
    if (growm < N) {
      _Float16* dst = xt + (size_t)growm * 128 + col;
#pragma unroll
      for (int n = 0; n < 8; ++n) dst[16 * n] = (_Float16)(f1 * acc[n][r] + f2 * hbv[n]);
    }
  }
}

// ---------- CSR build ----------
__global__ void k_hist(const int* __restrict__ dst, int* __restrict__ deg, int E) {
  int e = blockIdx.x * blockDim.x + threadIdx.x;
  if (e < E) atomicAdd(&deg[dst[e]], 1);
}

// single-block exclusive scan, int4-vectorized
__global__ __launch_bounds__(1024) void k_scan(const int* __restrict__ deg,
                                               int* __restrict__ offsets, int N) {
  __shared__ int waveSums[16];
  __shared__ int sCarry;
  const int t = threadIdx.x;
  const int lane = t & 63, wv = t >> 6;
  const int N4 = N >> 2;
  const int4* deg4 = (const int4*)deg;
  if (t == 0) sCarry = 0;
  __syncthreads();
  for (int base = 0; base < N4; base += 1024) {
    int i = base + t;
    int4 v = (i < N4) ? deg4[i] : make_int4(0, 0, 0, 0);
    int s0 = v.x, s1 = s0 + v.y, s2 = s1 + v.z, s3 = s2 + v.w;
    int incl = s3;
#pragma unroll
    for (int off = 1; off < 64; off <<= 1) {
      int u = __shfl_up(incl, off, 64);
      if (lane >= off) incl += u;
    }
    if (lane == 63) waveSums[wv] = incl;
    __syncthreads();
    if (wv == 0) {
      int s = (lane < 16) ? waveSums[lane] : 0;
#pragma unroll
      for (int off = 1; off < 16; off <<= 1) {
        int u = __shfl_up(s, off, 64);
        if (lane >= off) s += u;
      }
      if (lane < 16) waveSums[lane] = s;
    }
    __syncthreads();
    int C = sCarry + ((wv == 0) ? 0 : waveSums[wv - 1]) + (incl - s3);
    if (i < N4) ((int4*)offsets)[i] = make_int4(C, C + s0, C + s1, C + s2);
    __syncthreads();
    if (t == 0) sCarry += waveSums[15];
    __syncthreads();
  }
  if (t == 0) {
    int total = sCarry;
    for (int j = N4 << 2; j < N; ++j) {
      offsets[j] = total;
      total += deg[j];
    }
    offsets[N] = total;
  }
}

// scatter edges into CSR (packed {src, weight} in one 8B store)
__global__ void k_scatter(const int* __restrict__ src, const int* __restrict__ dst,
                          const float* __restrict__ ew, int* __restrict__ offsets,
                          uint2* __restrict__ csr, int E) {
  int e = blockIdx.x * blockDim.x + threadIdx.x;
  if (e < E) {
    int p = atomicAdd(&offsets[dst[e]], 1);
    csr[p] = make_uint2((unsigned)src[e], __float_as_uint(ew[e]));
  }
}

// ---------- fused: gather-aggregate (fp16 xt) + expmap/relu/expmap tail ----------
__global__ __launch_bounds__(256) void k_agg_final(
    const h2* __restrict__ xt, const uint2* __restrict__ csr,
    const int* __restrict__ offsets, const int* __restrict__ deg,
    float* __restrict__ out, int N) {
  int n = blockIdx.x * 4 + (threadIdx.x >> 6);
  int lane = threadIdx.x & 63;
  if (n >= N) return;
  int end = offsets[n];  // post-scatter: end of segment
  int e = end - deg[n];
  float a0 = 0.f, a1 = 0.f;
  for (; e + 4 <= end; e += 4) {
    uint2 c0 = csr[e], c1 = csr[e + 1], c2 = csr[e + 2], c3 = csr[e + 3];
    h2 u0 = xt[(size_t)c0.x * 64 + lane];
    h2 u1 = xt[(size_t)c1.x * 64 + lane];
    h2 u2 = xt[(size_t)c2.x * 64 + lane];
    h2 u3 = xt[(size_t)c3.x * 64 + lane];
    float w0 = __uint_as_float(c0.y), w1 = __uint_as_float(c1.y);
    float w2 = __uint_as_float(c2.y), w3 = __uint_as_float(c3.y);
    a0 = fmaf(w0, (float)u0[0], a0);
    a1 = fmaf(w0, (float)u0[1], a1);
    a0 = fmaf(w1, (float)u1[0], a0);
    a1 = fmaf(w1, (float)u1[1], a1);
    a0 = fmaf(w2, (float)u2[0], a0);
    a1 = fmaf(w2, (float)u2[1], a1);
    a0 = fmaf(w3, (float)u3[0], a0);
    a1 = fmaf(w3, (float)u3[1], a1);
  }
  for (; e < end; ++e) {
    uint2 c0 = csr[e];
    h2 u0 = xt[(size_t)c0.x * 64 + lane];
    float w0 = __uint_as_float(c0.y);
    a0 = fmaf(w0, (float)u0[0], a0);
    a1 = fmaf(w0, (float)u0[1], a1);
  }
  float v0 = a0, v1 = a1;
  expmap0_proj(v0, v1);
  float nn = fmaxf(sqrtf(wave_sum(v0 * v0 + v1 * v1)), 1e-15f);
  float s = artanh_c(nn) / nn;
  v0 = fmaxf(v0 * s, 0.0f);
  v1 = fmaxf(v1 * s, 0.0f);
  expmap0_proj(v0, v1);
  ((float2*)(out + (size_t)n * 128))[lane] = make_float2(v0, v1);
}

// ---------- fallback path: edge atomics (fp16 xt) ----------
__global__ void k_edge(const h2* __restrict__ xt, const float* __restrict__ ew,
                       const int* __restrict__ src, const int* __restrict__ dst,
                       float* __restrict__ agg, int E) {
  int tid = blockIdx.x * blockDim.x + threadIdx.x;
  int gw = tid >> 6;
  int lane = tid & 63;
  int nw = (gridDim.x * blockDim.x) >> 6;
  for (int e = gw; e < E; e += nw) {
    int s = src[e];
    int d = dst[e];
    float wgt = ew[e];
    h2 v = xt[(size_t)s * 64 + lane];
    float* base = agg + (size_t)d * 128 + 2 * lane;
    unsafeAtomicAdd(base, (float)v[0] * wgt);
    unsafeAtomicAdd(base + 1, (float)v[1] * wgt);
  }
}

__global__ void k_final(const float* __restrict__ agg, float* __restrict__ out, int N) {
  int gw = blockIdx.x * 4 + (threadIdx.x >> 6);
  int lane = threadIdx.x & 63;
  if (gw >= N) return;
  float2 v = ((const float2*)(agg + (size_t)gw * 128))[lane];
  float v0 = v.x, v1 = v.y;
  expmap0_proj(v0, v1);
  float n = fmaxf(sqrtf(wave_sum(v0 * v0 + v1 * v1)), 1e-15f);
  float s = artanh_c(n) / n;
  v0 = fmaxf(v0 * s, 0.0f);
  v1 = fmaxf(v1 * s, 0.0f);
  expmap0_proj(v0, v1);
  ((float2*)(out + (size_t)gw * 128))[lane] = make_float2(v0, v1);
}

static inline size_t pad256(size_t x) { return (x + 255) & ~(size_t)255; }

extern "C" void kernel_launch(void* const* d_in, const int* in_sizes, int n_in,
                              void* d_out, int out_size, void* d_ws, size_t ws_size,
                              hipStream_t stream) {
  const float* x = (const float*)d_in[0];
  const float* W = (const float*)d_in[1];
  const float* b = (const float*)d_in[2];
  const float* ew = (const float*)d_in[3];
  const int* src = (const int*)d_in[4];
  const int* dst = (const int*)d_in[5];
  float* out = (float*)d_out;
  const int N = in_sizes[0] / 128;
  const int E = in_sizes[3];

  char* p = (char*)d_ws;
  float* wsb = (float*)p;    p += 1024;
  int* deg = (int*)p;        p += pad256((size_t)N * 4);
  int* offsets = (int*)p;    p += pad256((size_t)(N + 1) * 4);
  uint2* csr = (uint2*)p;    p += pad256((size_t)E * 8);
  _Float16* xt = (_Float16*)p;  p += (size_t)N * 256;  // N*128 halfs
  size_t need = (size_t)(p - (char*)d_ws);

  if (ws_size >= need) {
    (void)hipMemsetAsync(deg, 0, (size_t)N * 4, stream);
    k_bias<<<1, 64, 0, stream>>>(b, wsb);
    k_hist<<<(E + 255) / 256, 256, 0, stream>>>(dst, deg, E);
    k_scan<<<1, 1024, 0, stream>>>(deg, offsets, N);
    k_linear<<<(N + 63) / 64, 256, 0, stream>>>(x, W, wsb, xt, N);
    k_scatter<<<(E + 255) / 256, 256, 0, stream>>>(src, dst, ew, offsets, csr, E);
    k_agg_final<<<(N + 3) / 4, 256, 0, stream>>>((const h2*)xt, csr, offsets, deg, out, N);
  } else {
    float* wsb2 = (float*)d_ws;
    float* agg = wsb2 + 256;
    _Float16* xth = (_Float16*)d_out;  // first 12.8 MB of out reused as fp16 xt staging
    (void)hipMemsetAsync(agg, 0, (size_t)N * 128 * sizeof(float), stream);
    k_bias<<<1, 64, 0, stream>>>(b, wsb2);
    k_linear<<<(N + 63) / 64, 256, 0, stream>>>(x, W, wsb2, xth, N);
    k_edge<<<2048, 256, 0, stream>>>((const h2*)xth, ew, src, dst, agg, E);
    k_final<<<(N + 3) / 4, 256, 0, stream>>>(agg, out, N);
  }
}

// Round 8
// 137.899 us; speedup vs baseline: 4.9759x; 1.1660x over previous
//
#include <hip/hip_runtime.h>
#include <math.h>

#define MAXNORM 0.996f  // (1 - 4e-3) / sqrt(c), c = 1

typedef _Float16 h2 __attribute__((ext_vector_type(2)));
typedef _Float16 h8v __attribute__((ext_vector_type(8)));
typedef float f4v __attribute__((ext_vector_type(4)));

__device__ __forceinline__ float wave_sum(float v) {
#pragma unroll
  for (int off = 32; off > 0; off >>= 1) v += __shfl_xor(v, off, 64);
  return v;
}

__device__ __forceinline__ float artanh_c(float x) {
  x = fminf(fmaxf(x, -1.0f + 1e-7f), 1.0f - 1e-7f);
  return 0.5f * (log1pf(x) - log1pf(-x));
}

__device__ __forceinline__ void proj2(float& v0, float& v1) {
  float n = fmaxf(sqrtf(wave_sum(v0 * v0 + v1 * v1)), 1e-15f);
  if (n > MAXNORM) {
    float s = MAXNORM / n;
    v0 *= s;
    v1 *= s;
  }
}

__device__ __forceinline__ void expmap0_proj(float& v0, float& v1) {
  float n = fmaxf(sqrtf(wave_sum(v0 * v0 + v1 * v1)), 1e-15f);
  float s = tanhf(n) / n;
  v0 *= s;
  v1 *= s;
  proj2(v0, v1);
}

// ---------- K2 fat kernel: MFMA GEMM + in-block bias + fused histogram ----------
// Blocks [0, nbLin): linear. Blocks [nbLin, grid): histogram over dst (grid-stride).
// Linear: mfma_f32_16x16x32_f16; 64 rows/block, 4 waves, 16-row stripe/wave.
// A (x): lane row=lane&15, k=(lane>>4)*8+j (global). B (W^T): col=lane&15, same k
// (LDS fp16, XOR-swizzled). D: col=lane&15, row=(lane>>4)*4+reg.
__global__ __launch_bounds__(256, 4) void k_lin_hist(
    const float* __restrict__ x, const float* __restrict__ W,
    const float* __restrict__ b, const int* __restrict__ dst,
    int* __restrict__ deg, _Float16* __restrict__ xt, int N, int E, int nbLin) {
  if ((int)blockIdx.x >= nbLin) {  // ---- histogram branch ----
    int id = blockIdx.x - nbLin;
    int stride = (gridDim.x - nbLin) * 256;
    for (int e = id * 256 + threadIdx.x; e < E; e += stride)
      atomicAdd(&deg[dst[e]], 1);
    return;
  }

  __shared__ _Float16 WsH[128 * 128];  // 32 KB
  __shared__ float biasLds[132];
  const int t = threadIdx.x;
  const int lane = t & 63;
  const int wv = t >> 6;

  // stage W fp16, swizzle h-index: k ^= (o&7)<<3
  const float4* W4 = (const float4*)W;
#pragma unroll
  for (int i = 0; i < 16; ++i) {
    int f = t + 256 * i;  // 4096 float4 total
    int o = f >> 5;
    int k4 = (f & 31) << 2;
    float4 v = W4[f];
    unsigned lo = __builtin_bit_cast(unsigned, __builtin_amdgcn_cvt_pkrtz(v.x, v.y));
    unsigned hi = __builtin_bit_cast(unsigned, __builtin_amdgcn_cvt_pkrtz(v.z, v.w));
    *(uint2*)&WsH[o * 128 + (k4 ^ ((o & 7) << 3))] = make_uint2(lo, hi);
  }

  // wave 0: hyp_bias = proj(expmap0(b)) -> LDS
  if (t < 64) {
    float b0 = b[t], b1 = b[t + 64];
    float nb = fmaxf(sqrtf(wave_sum(b0 * b0 + b1 * b1)), 1e-15f);
    float s = tanhf(nb) / nb;
    float h0 = b0 * s, h1 = b1 * s;
    proj2(h0, h1);
    float y2w = wave_sum(h0 * h0 + h1 * h1);
    biasLds[t] = h0;
    biasLds[t + 64] = h1;
    if (t == 0) biasLds[128] = y2w;
  }
  __syncthreads();

  const int col = lane & 15;  // o within tile; also A-row within stripe
  const int g = lane >> 4;    // k-group 0..3
  float hbv[8];
#pragma unroll
  for (int n = 0; n < 8; ++n) hbv[n] = biasLds[col + 16 * n];
  const float y2 = biasLds[128];

  const int stripe0 = blockIdx.x * 64 + wv * 16;
  int arow = stripe0 + col;
  if (arow >= N) arow = N - 1;  // clamp; stores guarded
  const float4* X4 = (const float4*)x;

  // A fragments for 4 K-steps + in-register ||x_row||^2
  h8v af[4];
  float pxr = 0.f;
#pragma unroll
  for (int s = 0; s < 4; ++s) {
    float4 a = X4[(size_t)arow * 32 + 8 * s + 2 * g];
    float4 c = X4[(size_t)arow * 32 + 8 * s + 2 * g + 1];
    pxr = fmaf(a.x, a.x, pxr);
    pxr = fmaf(a.y, a.y, pxr);
    pxr = fmaf(a.z, a.z, pxr);
    pxr = fmaf(a.w, a.w, pxr);
    pxr = fmaf(c.x, c.x, pxr);
    pxr = fmaf(c.y, c.y, pxr);
    pxr = fmaf(c.z, c.z, pxr);
    pxr = fmaf(c.w, c.w, pxr);
    union {
      uint4 u;
      h8v h;
    } cv;
    cv.u = make_uint4(
        __builtin_bit_cast(unsigned, __builtin_amdgcn_cvt_pkrtz(a.x, a.y)),
        __builtin_bit_cast(unsigned, __builtin_amdgcn_cvt_pkrtz(a.z, a.w)),
        __builtin_bit_cast(unsigned, __builtin_amdgcn_cvt_pkrtz(c.x, c.y)),
        __builtin_bit_cast(unsigned, __builtin_amdgcn_cvt_pkrtz(c.z, c.w)));
    af[s] = cv.h;
  }
  pxr += __shfl_xor(pxr, 16, 64);
  pxr += __shfl_xor(pxr, 32, 64);
  // lane i (i<16) holds ||x_{stripe0+i}||^2

  f4v acc[8];
  const f4v zero = {0.f, 0.f, 0.f, 0.f};
#pragma unroll
  for (int n = 0; n < 8; ++n) acc[n] = zero;

  const int osw = (col & 7) << 3;  // (o&7) == (col&7) since o = 16n + col
#pragma unroll
  for (int n = 0; n < 8; ++n) {
    const int obase = (16 * n + col) * 128;
#pragma unroll
    for (int s = 0; s < 4; ++s) {
      h8v bf = *(const h8v*)&WsH[obase + ((32 * s + 8 * g) ^ osw)];
      acc[n] = __builtin_amdgcn_mfma_f32_16x16x32_f16(af[s], bf, acc[n], 0, 0, 0);
    }
  }

  // fused HypLinear tail; D row i = g*4 + r, o = col + 16n
#pragma unroll
  for (int r = 0; r < 4; ++r) {
    float pm = 0.f, pxy = 0.f;
#pragma unroll
    for (int n = 0; n < 8; ++n) {
      float v = acc[n][r];
      pm = fmaf(v, v, pm);
      pxy = fmaf(v, hbv[n], pxy);
    }
#pragma unroll
    for (int off = 1; off < 16; off <<= 1) {
      pm += __shfl_xor(pm, off, 64);
      pxy += __shfl_xor(pxy, off, 64);
    }
    const int irow = g * 4 + r;
    float px = __shfl(pxr, irow, 64);
    float xn = fmaxf(sqrtf(px), 1e-15f);
    float mxn = fmaxf(sqrtf(pm), 1e-15f);
    float s1 = tanhf(mxn / xn * artanh_c(xn)) / mxn;
    if (pm == 0.0f) s1 = 0.0f;
    float nv = s1 * mxn;
    if (nv > MAXNORM) {
      s1 *= MAXNORM / nv;
      nv = MAXNORM;
    }
    float x2 = nv * nv;
    float xy = s1 * pxy;
    float A = 1.0f + 2.0f * xy + y2;
    float B = 1.0f - x2;
    float den = fmaxf(1.0f + 2.0f * xy + x2 * y2, 1e-15f);
    float rn2 = fmaxf(A * A * x2 + 2.0f * A * B * xy + B * B * y2, 0.0f);
    float rn = sqrtf(rn2) / den;
    float gs = 1.0f;
    if (rn > MAXNORM) gs = MAXNORM / rn;
    float ng = fmaxf(fminf(rn, MAXNORM), 1e-15f);
    float slog = artanh_c(ng) / ng;
    float ftot = slog * gs / den;
    float f1 = ftot * A * s1;
    float f2 = ftot * B;
    const int growm = stripe0 + irow;
    if (growm < N) {
      _Float16* dp = xt + (size_t)growm * 128 + col;
#pragma unroll
      for (int n = 0; n < 8; ++n) dp[16 * n] = (_Float16)(f1 * acc[n][r] + f2 * hbv[n]);
    }
  }
}

// single-block exclusive scan, int4-vectorized
__global__ __launch_bounds__(1024) void k_scan(const int* __restrict__ deg,
                                               int* __restrict__ offsets, int N) {
  __shared__ int waveSums[16];
  __shared__ int sCarry;
  const int t = threadIdx.x;
  const int lane = t & 63, wv = t >> 6;
  const int N4 = N >> 2;
  const int4* deg4 = (const int4*)deg;
  if (t == 0) sCarry = 0;
  __syncthreads();
  for (int base = 0; base < N4; base += 1024) {
    int i = base + t;
    int4 v = (i < N4) ? deg4[i] : make_int4(0, 0, 0, 0);
    int s0 = v.x, s1 = s0 + v.y, s2 = s1 + v.z, s3 = s2 + v.w;
    int incl = s3;
#pragma unroll
    for (int off = 1; off < 64; off <<= 1) {
      int u = __shfl_up(incl, off, 64);
      if (lane >= off) incl += u;
    }
    if (lane == 63) waveSums[wv] = incl;
    __syncthreads();
    if (wv == 0) {
      int s = (lane < 16) ? waveSums[lane] : 0;
#pragma unroll
      for (int off = 1; off < 16; off <<= 1) {
        int u = __shfl_up(s, off, 64);
        if (lane >= off) s += u;
      }
      if (lane < 16) waveSums[lane] = s;
    }
    __syncthreads();
    int C = sCarry + ((wv == 0) ? 0 : waveSums[wv - 1]) + (incl - s3);
    if (i < N4) ((int4*)offsets)[i] = make_int4(C, C + s0, C + s1, C + s2);
    __syncthreads();
    if (t == 0) sCarry += waveSums[15];
    __syncthreads();
  }
  if (t == 0) {
    int total = sCarry;
    for (int j = N4 << 2; j < N; ++j) {
      offsets[j] = total;
      total += deg[j];
    }
    offsets[N] = total;
  }
}

// scatter edges into CSR (packed {src, weight} in one 8B store)
__global__ void k_scatter(const int* __restrict__ src, const int* __restrict__ dst,
                          const float* __restrict__ ew, int* __restrict__ offsets,
                          uint2* __restrict__ csr, int E) {
  int e = blockIdx.x * blockDim.x + threadIdx.x;
  if (e < E) {
    int p = atomicAdd(&offsets[dst[e]], 1);
    csr[p] = make_uint2((unsigned)src[e], __float_as_uint(ew[e]));
  }
}

// ---------- fused gather-aggregate, SCALARIZED (s_load csr, SALU addresses) ----------
__global__ __launch_bounds__(256) void k_agg_final(
    const _Float16* __restrict__ xt, const uint2* __restrict__ csr,
    const int* __restrict__ offsets, const int* __restrict__ deg,
    float* __restrict__ out, int N) {
  int n0 = blockIdx.x * 4 + (threadIdx.x >> 6);
  const int lane = threadIdx.x & 63;
  if (n0 >= N) return;
  const int n = __builtin_amdgcn_readfirstlane(n0);  // wave-uniform -> SGPR
  const int end = offsets[n];
  int e = end - deg[n];
  float a0 = 0.f, a1 = 0.f;
  for (; e + 8 <= end; e += 8) {
    uint2 c[8];
#pragma unroll
    for (int i = 0; i < 8; ++i) c[i] = csr[e + i];  // uniform addr -> s_load
    h2 u[8];
#pragma unroll
    for (int i = 0; i < 8; ++i) {
      const h2* r = (const h2*)xt + (((size_t)c[i].x) << 6);  // SALU base
      u[i] = r[lane];
    }
#pragma unroll
    for (int i = 0; i < 8; ++i) {
      float w = __uint_as_float(c[i].y);  // SGPR operand
      a0 = fmaf(w, (float)u[i][0], a0);
      a1 = fmaf(w, (float)u[i][1], a1);
    }
  }
  for (; e < end; ++e) {
    uint2 c0 = csr[e];
    const h2* r = (const h2*)xt + (((size_t)c0.x) << 6);
    h2 u0 = r[lane];
    float w0 = __uint_as_float(c0.y);
    a0 = fmaf(w0, (float)u0[0], a0);
    a1 = fmaf(w0, (float)u0[1], a1);
  }
  float v0 = a0, v1 = a1;
  expmap0_proj(v0, v1);
  float nn = fmaxf(sqrtf(wave_sum(v0 * v0 + v1 * v1)), 1e-15f);
  float s = artanh_c(nn) / nn;
  v0 = fmaxf(v0 * s, 0.0f);
  v1 = fmaxf(v1 * s, 0.0f);
  expmap0_proj(v0, v1);
  ((float2*)(out + (size_t)n * 128))[lane] = make_float2(v0, v1);
}

// ---------- fallback path: edge atomics (fp16 xt) ----------
__global__ void k_edge(const h2* __restrict__ xt, const float* __restrict__ ew,
                       const int* __restrict__ src, const int* __restrict__ dst,
                       float* __restrict__ agg, int E) {
  int tid = blockIdx.x * blockDim.x + threadIdx.x;
  int gw = tid >> 6;
  int lane = tid & 63;
  int nw = (gridDim.x * blockDim.x) >> 6;
  for (int e = gw; e < E; e += nw) {
    int s = src[e];
    int d = dst[e];
    float wgt = ew[e];
    h2 v = xt[(size_t)s * 64 + lane];
    float* base = agg + (size_t)d * 128 + 2 * lane;
    unsafeAtomicAdd(base, (float)v[0] * wgt);
    unsafeAtomicAdd(base + 1, (float)v[1] * wgt);
  }
}

__global__ void k_final(const float* __restrict__ agg, float* __restrict__ out, int N) {
  int gw = blockIdx.x * 4 + (threadIdx.x >> 6);
  int lane = threadIdx.x & 63;
  if (gw >= N) return;
  float2 v = ((const float2*)(agg + (size_t)gw * 128))[lane];
  float v0 = v.x, v1 = v.y;
  expmap0_proj(v0, v1);
  float n = fmaxf(sqrtf(wave_sum(v0 * v0 + v1 * v1)), 1e-15f);
  float s = artanh_c(n) / n;
  v0 = fmaxf(v0 * s, 0.0f);
  v1 = fmaxf(v1 * s, 0.0f);
  expmap0_proj(v0, v1);
  ((float2*)(out + (size_t)gw * 128))[lane] = make_float2(v0, v1);
}

static inline size_t pad256(size_t x) { return (x + 255) & ~(size_t)255; }

extern "C" void kernel_launch(void* const* d_in, const int* in_sizes, int n_in,
                              void* d_out, int out_size, void* d_ws, size_t ws_size,
                              hipStream_t stream) {
  const float* x = (const float*)d_in[0];
  const float* W = (const float*)d_in[1];
  const float* b = (const float*)d_in[2];
  const float* ew = (const float*)d_in[3];
  const int* src = (const int*)d_in[4];
  const int* dst = (const int*)d_in[5];
  float* out = (float*)d_out;
  const int N = in_sizes[0] / 128;
  const int E = in_sizes[3];

  char* p = (char*)d_ws;
  int* deg = (int*)p;           p += pad256((size_t)N * 4);
  int* offsets = (int*)p;       p += pad256((size_t)(N + 1) * 4);
  uint2* csr = (uint2*)p;       p += pad256((size_t)E * 8);
  _Float16* xt = (_Float16*)p;  p += (size_t)N * 256;  // N*128 halfs
  size_t need = (size_t)(p - (char*)d_ws);

  const int nbLin = (N + 63) / 64;
  if (ws_size >= need) {
    (void)hipMemsetAsync(deg, 0, (size_t)N * 4, stream);
    k_lin_hist<<<nbLin + 512, 256, 0, stream>>>(x, W, b, dst, deg, xt, N, E, nbLin);
    k_scan<<<1, 1024, 0, stream>>>(deg, offsets, N);
    k_scatter<<<(E + 255) / 256, 256, 0, stream>>>(src, dst, ew, offsets, csr, E);
    k_agg_final<<<(N + 3) / 4, 256, 0, stream>>>(xt, csr, offsets, deg, out, N);
  } else {
    float* agg = (float*)d_ws;
    _Float16* xth = (_Float16*)d_out;  // first 12.8 MB of out reused as fp16 xt staging
    (void)hipMemsetAsync(agg, 0, (size_t)N * 128 * sizeof(float), stream);
    k_lin_hist<<<nbLin, 256, 0, stream>>>(x, W, b, nullptr, nullptr, xth, N, 0, nbLin);
    k_edge<<<2048, 256, 0, stream>>>((const h2*)xth, ew, src, dst, agg, E);
    k_final<<<(N + 3) / 4, 256, 0, stream>>>(agg, out, N);
  }
}

// Round 9
// 120.550 us; speedup vs baseline: 5.6921x; 1.1439x over previous
//
#include <hip/hip_runtime.h>
#include <math.h>

#define MAXNORM 0.996f  // (1 - 4e-3) / sqrt(c), c = 1

typedef _Float16 h2 __attribute__((ext_vector_type(2)));
typedef _Float16 h8v __attribute__((ext_vector_type(8)));
typedef float f4v __attribute__((ext_vector_type(4)));

__device__ __forceinline__ float wave_sum(float v) {
#pragma unroll
  for (int off = 32; off > 0; off >>= 1) v += __shfl_xor(v, off, 64);
  return v;
}

// x >= 0; branch-free tanh via v_exp_f32
__device__ __forceinline__ float fast_tanh(float x) {
  float e = __expf(2.0f * x);
  return (e - 1.0f) * __builtin_amdgcn_rcpf(e + 1.0f);
}

// 0 <= x <= ~0.9961; branch-free artanh via v_log_f32
__device__ __forceinline__ float fast_artanh(float x) {
  x = fminf(x, 1.0f - 1e-7f);
  return 0.5f * __logf((1.0f + x) * __builtin_amdgcn_rcpf(1.0f - x));
}

__device__ __forceinline__ void proj2(float& v0, float& v1) {
  float n = fmaxf(sqrtf(wave_sum(v0 * v0 + v1 * v1)), 1e-15f);
  if (n > MAXNORM) {
    float s = MAXNORM / n;
    v0 *= s;
    v1 *= s;
  }
}

// ---------- K2 fat kernel: MFMA GEMM + in-block bias + fused histogram ----------
__global__ __launch_bounds__(256, 4) void k_lin_hist(
    const float* __restrict__ x, const float* __restrict__ W,
    const float* __restrict__ b, const int* __restrict__ dst,
    int* __restrict__ deg, _Float16* __restrict__ xt, int N, int E, int nbLin) {
  if ((int)blockIdx.x >= nbLin) {  // ---- histogram branch ----
    int id = blockIdx.x - nbLin;
    int stride = (gridDim.x - nbLin) * 256;
    for (int e = id * 256 + threadIdx.x; e < E; e += stride)
      atomicAdd(&deg[dst[e]], 1);
    return;
  }

  __shared__ _Float16 WsH[128 * 128];  // 32 KB
  __shared__ float biasLds[132];
  const int t = threadIdx.x;
  const int lane = t & 63;
  const int wv = t >> 6;

  // stage W fp16, swizzle h-index: k ^= (o&7)<<3
  const float4* W4 = (const float4*)W;
#pragma unroll
  for (int i = 0; i < 16; ++i) {
    int f = t + 256 * i;  // 4096 float4 total
    int o = f >> 5;
    int k4 = (f & 31) << 2;
    float4 v = W4[f];
    unsigned lo = __builtin_bit_cast(unsigned, __builtin_amdgcn_cvt_pkrtz(v.x, v.y));
    unsigned hi = __builtin_bit_cast(unsigned, __builtin_amdgcn_cvt_pkrtz(v.z, v.w));
    *(uint2*)&WsH[o * 128 + (k4 ^ ((o & 7) << 3))] = make_uint2(lo, hi);
  }

  // wave 0: hyp_bias = proj(expmap0(b)) -> LDS
  if (t < 64) {
    float b0 = b[t], b1 = b[t + 64];
    float nb = fmaxf(sqrtf(wave_sum(b0 * b0 + b1 * b1)), 1e-15f);
    float s = fast_tanh(nb) * __builtin_amdgcn_rcpf(nb);
    float h0 = b0 * s, h1 = b1 * s;
    proj2(h0, h1);
    float y2w = wave_sum(h0 * h0 + h1 * h1);
    biasLds[t] = h0;
    biasLds[t + 64] = h1;
    if (t == 0) biasLds[128] = y2w;
  }
  __syncthreads();

  const int col = lane & 15;  // o within tile; also A-row within stripe
  const int g = lane >> 4;    // k-group 0..3
  float hbv[8];
#pragma unroll
  for (int n = 0; n < 8; ++n) hbv[n] = biasLds[col + 16 * n];
  const float y2 = biasLds[128];

  const int stripe0 = blockIdx.x * 64 + wv * 16;
  int arow = stripe0 + col;
  if (arow >= N) arow = N - 1;  // clamp; stores guarded
  const float4* X4 = (const float4*)x;

  // A fragments for 4 K-steps + in-register ||x_row||^2
  h8v af[4];
  float pxr = 0.f;
#pragma unroll
  for (int s = 0; s < 4; ++s) {
    float4 a = X4[(size_t)arow * 32 + 8 * s + 2 * g];
    float4 c = X4[(size_t)arow * 32 + 8 * s + 2 * g + 1];
    pxr = fmaf(a.x, a.x, pxr);
    pxr = fmaf(a.y, a.y, pxr);
    pxr = fmaf(a.z, a.z, pxr);
    pxr = fmaf(a.w, a.w, pxr);
    pxr = fmaf(c.x, c.x, pxr);
    pxr = fmaf(c.y, c.y, pxr);
    pxr = fmaf(c.z, c.z, pxr);
    pxr = fmaf(c.w, c.w, pxr);
    union {
      uint4 u;
      h8v h;
    } cv;
    cv.u = make_uint4(
        __builtin_bit_cast(unsigned, __builtin_amdgcn_cvt_pkrtz(a.x, a.y)),
        __builtin_bit_cast(unsigned, __builtin_amdgcn_cvt_pkrtz(a.z, a.w)),
        __builtin_bit_cast(unsigned, __builtin_amdgcn_cvt_pkrtz(c.x, c.y)),
        __builtin_bit_cast(unsigned, __builtin_amdgcn_cvt_pkrtz(c.z, c.w)));
    af[s] = cv.h;
  }
  pxr += __shfl_xor(pxr, 16, 64);
  pxr += __shfl_xor(pxr, 32, 64);
  // lane i (i<16) holds ||x_{stripe0+i}||^2

  f4v acc[8];
  const f4v zero = {0.f, 0.f, 0.f, 0.f};
#pragma unroll
  for (int n = 0; n < 8; ++n) acc[n] = zero;

  const int osw = (col & 7) << 3;  // (o&7) == (col&7) since o = 16n + col
#pragma unroll
  for (int n = 0; n < 8; ++n) {
    const int obase = (16 * n + col) * 128;
#pragma unroll
    for (int s = 0; s < 4; ++s) {
      h8v bf = *(const h8v*)&WsH[obase + ((32 * s + 8 * g) ^ osw)];
      acc[n] = __builtin_amdgcn_mfma_f32_16x16x32_f16(af[s], bf, acc[n], 0, 0, 0);
    }
  }

  // fused HypLinear tail; D row i = g*4 + r, o = col + 16n
#pragma unroll
  for (int r = 0; r < 4; ++r) {
    float pm = 0.f, pxy = 0.f;
#pragma unroll
    for (int n = 0; n < 8; ++n) {
      float v = acc[n][r];
      pm = fmaf(v, v, pm);
      pxy = fmaf(v, hbv[n], pxy);
    }
#pragma unroll
    for (int off = 1; off < 16; off <<= 1) {
      pm += __shfl_xor(pm, off, 64);
      pxy += __shfl_xor(pxy, off, 64);
    }
    const int irow = g * 4 + r;
    float px = __shfl(pxr, irow, 64);
    float xn = fmaxf(sqrtf(px), 1e-15f);
    float mxn = fmaxf(sqrtf(pm), 1e-15f);
    float s1 = fast_tanh(mxn * __builtin_amdgcn_rcpf(xn) * fast_artanh(xn)) *
               __builtin_amdgcn_rcpf(mxn);
    if (pm == 0.0f) s1 = 0.0f;
    float nv = s1 * mxn;
    if (nv > MAXNORM) {
      s1 *= MAXNORM / nv;
      nv = MAXNORM;
    }
    float x2 = nv * nv;
    float xy = s1 * pxy;
    float A = 1.0f + 2.0f * xy + y2;
    float B = 1.0f - x2;
    float den = fmaxf(1.0f + 2.0f * xy + x2 * y2, 1e-15f);
    float rden = __builtin_amdgcn_rcpf(den);
    float rn2 = fmaxf(A * A * x2 + 2.0f * A * B * xy + B * B * y2, 0.0f);
    float rn = sqrtf(rn2) * rden;
    float gs = 1.0f;
    if (rn > MAXNORM) gs = MAXNORM / rn;
    float ng = fmaxf(fminf(rn, MAXNORM), 1e-15f);
    float slog = fast_artanh(ng) * __builtin_amdgcn_rcpf(ng);
    float ftot = slog * gs * rden;
    float f1 = ftot * A * s1;
    float f2 = ftot * B;
    const int growm = stripe0 + irow;
    if (growm < N) {
      _Float16* dp = xt + (size_t)growm * 128 + col;
#pragma unroll
      for (int n = 0; n < 8; ++n) dp[16 * n] = (_Float16)(f1 * acc[n][r] + f2 * hbv[n]);
    }
  }
}

// single-block exclusive scan, int4-vectorized
__global__ __launch_bounds__(1024) void k_scan(const int* __restrict__ deg,
                                               int* __restrict__ offsets, int N) {
  __shared__ int waveSums[16];
  __shared__ int sCarry;
  const int t = threadIdx.x;
  const int lane = t & 63, wv = t >> 6;
  const int N4 = N >> 2;
  const int4* deg4 = (const int4*)deg;
  if (t == 0) sCarry = 0;
  __syncthreads();
  for (int base = 0; base < N4; base += 1024) {
    int i = base + t;
    int4 v = (i < N4) ? deg4[i] : make_int4(0, 0, 0, 0);
    int s0 = v.x, s1 = s0 + v.y, s2 = s1 + v.z, s3 = s2 + v.w;
    int incl = s3;
#pragma unroll
    for (int off = 1; off < 64; off <<= 1) {
      int u = __shfl_up(incl, off, 64);
      if (lane >= off) incl += u;
    }
    if (lane == 63) waveSums[wv] = incl;
    __syncthreads();
    if (wv == 0) {
      int s = (lane < 16) ? waveSums[lane] : 0;
#pragma unroll
      for (int off = 1; off < 16; off <<= 1) {
        int u = __shfl_up(s, off, 64);
        if (lane >= off) s += u;
      }
      if (lane < 16) waveSums[lane] = s;
    }
    __syncthreads();
    int C = sCarry + ((wv == 0) ? 0 : waveSums[wv - 1]) + (incl - s3);
    if (i < N4) ((int4*)offsets)[i] = make_int4(C, C + s0, C + s1, C + s2);
    __syncthreads();
    if (t == 0) sCarry += waveSums[15];
    __syncthreads();
  }
  if (t == 0) {
    int total = sCarry;
    for (int j = N4 << 2; j < N; ++j) {
      offsets[j] = total;
      total += deg[j];
    }
    offsets[N] = total;
  }
}

// scatter edges into CSR (packed {src, weight} in one 8B store)
__global__ void k_scatter(const int* __restrict__ src, const int* __restrict__ dst,
                          const float* __restrict__ ew, int* __restrict__ offsets,
                          uint2* __restrict__ csr, int E) {
  int e = blockIdx.x * blockDim.x + threadIdx.x;
  if (e < E) {
    int p = atomicAdd(&offsets[dst[e]], 1);
    csr[p] = make_uint2((unsigned)src[e], __float_as_uint(ew[e]));
  }
}

// ---------- fused gather-aggregate: scalarized loads + ALGEBRAIC tail ----------
// tail: 2 interleaved reductions (||agg||^2, ||relu(agg)||^2); all norms scalar.
__global__ __launch_bounds__(256) void k_agg_final(
    const _Float16* __restrict__ xt, const uint2* __restrict__ csr,
    const int* __restrict__ offsets, const int* __restrict__ deg,
    float* __restrict__ out, int N) {
  int n0 = blockIdx.x * 4 + (threadIdx.x >> 6);
  const int lane = threadIdx.x & 63;
  if (n0 >= N) return;
  const int n = __builtin_amdgcn_readfirstlane(n0);  // wave-uniform -> SGPR
  const int end = offsets[n];
  int e = end - deg[n];
  float a0 = 0.f, a1 = 0.f;
  for (; e + 8 <= end; e += 8) {
    uint2 c[8];
#pragma unroll
    for (int i = 0; i < 8; ++i) c[i] = csr[e + i];  // uniform addr -> s_load
    h2 u[8];
#pragma unroll
    for (int i = 0; i < 8; ++i) {
      const h2* r = (const h2*)xt + (((size_t)c[i].x) << 6);  // SALU base
      u[i] = r[lane];
    }
#pragma unroll
    for (int i = 0; i < 8; ++i) {
      float w = __uint_as_float(c[i].y);  // SGPR operand
      a0 = fmaf(w, (float)u[i][0], a0);
      a1 = fmaf(w, (float)u[i][1], a1);
    }
  }
  for (; e < end; ++e) {
    uint2 c0 = csr[e];
    const h2* r = (const h2*)xt + (((size_t)c0.x) << 6);
    h2 u0 = r[lane];
    float w0 = __uint_as_float(c0.y);
    a0 = fmaf(w0, (float)u0[0], a0);
    a1 = fmaf(w0, (float)u0[1], a1);
  }

  // ---- algebraic tail ----
  float p0 = fmaxf(a0, 0.0f), p1 = fmaxf(a1, 0.0f);
  float an2 = a0 * a0 + a1 * a1;
  float pos2 = p0 * p0 + p1 * p1;
#pragma unroll
  for (int off = 32; off > 0; off >>= 1) {
    an2 += __shfl_xor(an2, off, 64);
    pos2 += __shfl_xor(pos2, off, 64);
  }
  // h = proj(expmap0(agg)): ||h|| = min(tanh(an), MAXNORM), factor fh
  float an = fmaxf(sqrtf(an2), 1e-15f);
  float th = fast_tanh(an);
  float fh = th * __builtin_amdgcn_rcpf(an);
  float hn = th;
  if (th > MAXNORM) {
    fh = MAXNORM * __builtin_amdgcn_rcpf(an);
    hn = MAXNORM;
  }
  // t = relu(logmap0(h)) = c1 * max(agg, 0), c1 = fh * artanh(hn)/hn
  float hn_c = fmaxf(hn, 1e-15f);
  float c1 = fh * fast_artanh(hn_c) * __builtin_amdgcn_rcpf(hn_c);
  // out = proj(expmap0(t)): ||t|| = c1*sqrt(pos2)
  float tn = fmaxf(c1 * sqrtf(pos2), 1e-15f);
  float ts = fast_tanh(tn);
  float s2 = ts * __builtin_amdgcn_rcpf(tn);
  float gs = 1.0f;
  if (ts > MAXNORM) gs = MAXNORM * __builtin_amdgcn_rcpf(ts);
  float f = s2 * gs * c1;
  ((float2*)(out + (size_t)n * 128))[lane] = make_float2(f * p0, f * p1);
}

// ---------- fallback path: edge atomics (fp16 xt) ----------
__global__ void k_edge(const h2* __restrict__ xt, const float* __restrict__ ew,
                       const int* __restrict__ src, const int* __restrict__ dst,
                       float* __restrict__ agg, int E) {
  int tid = blockIdx.x * blockDim.x + threadIdx.x;
  int gw = tid >> 6;
  int lane = tid & 63;
  int nw = (gridDim.x * blockDim.x) >> 6;
  for (int e = gw; e < E; e += nw) {
    int s = src[e];
    int d = dst[e];
    float wgt = ew[e];
    h2 v = xt[(size_t)s * 64 + lane];
    float* base = agg + (size_t)d * 128 + 2 * lane;
    unsafeAtomicAdd(base, (float)v[0] * wgt);
    unsafeAtomicAdd(base + 1, (float)v[1] * wgt);
  }
}

__global__ void k_final(const float* __restrict__ agg, float* __restrict__ out, int N) {
  int gw = blockIdx.x * 4 + (threadIdx.x >> 6);
  int lane = threadIdx.x & 63;
  if (gw >= N) return;
  float2 v = ((const float2*)(agg + (size_t)gw * 128))[lane];
  float a0 = v.x, a1 = v.y;
  float p0 = fmaxf(a0, 0.0f), p1 = fmaxf(a1, 0.0f);
  float an2 = a0 * a0 + a1 * a1;
  float pos2 = p0 * p0 + p1 * p1;
#pragma unroll
  for (int off = 32; off > 0; off >>= 1) {
    an2 += __shfl_xor(an2, off, 64);
    pos2 += __shfl_xor(pos2, off, 64);
  }
  float an = fmaxf(sqrtf(an2), 1e-15f);
  float th = fast_tanh(an);
  float fh = th * __builtin_amdgcn_rcpf(an);
  float hn = th;
  if (th > MAXNORM) {
    fh = MAXNORM * __builtin_amdgcn_rcpf(an);
    hn = MAXNORM;
  }
  float hn_c = fmaxf(hn, 1e-15f);
  float c1 = fh * fast_artanh(hn_c) * __builtin_amdgcn_rcpf(hn_c);
  float tn = fmaxf(c1 * sqrtf(pos2), 1e-15f);
  float ts = fast_tanh(tn);
  float s2 = ts * __builtin_amdgcn_rcpf(tn);
  float gs = 1.0f;
  if (ts > MAXNORM) gs = MAXNORM * __builtin_amdgcn_rcpf(ts);
  float f = s2 * gs * c1;
  ((float2*)(out + (size_t)gw * 128))[lane] = make_float2(f * p0, f * p1);
}

static inline size_t pad256(size_t x) { return (x + 255) & ~(size_t)255; }

extern "C" void kernel_launch(void* const* d_in, const int* in_sizes, int n_in,
                              void* d_out, int out_size, void* d_ws, size_t ws_size,
                              hipStream_t stream) {
  const float* x = (const float*)d_in[0];
  const float* W = (const float*)d_in[1];
  const float* b = (const float*)d_in[2];
  const float* ew = (const float*)d_in[3];
  const int* src = (const int*)d_in[4];
  const int* dst = (const int*)d_in[5];
  float* out = (float*)d_out;
  const int N = in_sizes[0] / 128;
  const int E = in_sizes[3];

  char* p = (char*)d_ws;
  int* deg = (int*)p;           p += pad256((size_t)N * 4);
  int* offsets = (int*)p;       p += pad256((size_t)(N + 1) * 4);
  uint2* csr = (uint2*)p;       p += pad256((size_t)E * 8);
  _Float16* xt = (_Float16*)p;  p += (size_t)N * 256;  // N*128 halfs
  size_t need = (size_t)(p - (char*)d_ws);

  const int nbLin = (N + 63) / 64;
  if (ws_size >= need) {
    (void)hipMemsetAsync(deg, 0, (size_t)N * 4, stream);
    k_lin_hist<<<nbLin + 512, 256, 0, stream>>>(x, W, b, dst, deg, xt, N, E, nbLin);
    k_scan<<<1, 1024, 0, stream>>>(deg, offsets, N);
    k_scatter<<<(E + 255) / 256, 256, 0, stream>>>(src, dst, ew, offsets, csr, E);
    k_agg_final<<<(N + 3) / 4, 256, 0, stream>>>(xt, csr, offsets, deg, out, N);
  } else {
    float* agg = (float*)d_ws;
    _Float16* xth = (_Float16*)d_out;  // first 12.8 MB of out reused as fp16 xt staging
    (void)hipMemsetAsync(agg, 0, (size_t)N * 128 * sizeof(float), stream);
    k_lin_hist<<<nbLin, 256, 0, stream>>>(x, W, b, nullptr, nullptr, xth, N, 0, nbLin);
    k_edge<<<2048, 256, 0, stream>>>((const h2*)xth, ew, src, dst, agg, E);
    k_final<<<(N + 3) / 4, 256, 0, stream>>>(agg, out, N);
  }
}